// Round 1
// baseline (1018.475 us; speedup 1.0000x reference)
//
#include <hip/hip_runtime.h>
#include <hip/hip_bf16.h>

#define NN 50000
#define NE 500000
#define C 128
#define BN_EPS 1e-5f
#define NEG 0.01f

// ---------------- zero ----------------
__global__ void zero_kernel(float* __restrict__ p, long n) {
    long i = (long)blockIdx.x * blockDim.x + threadIdx.x;
    long s = (long)gridDim.x * blockDim.x;
    for (; i < n; i += s) p[i] = 0.f;
}

// ---------------- cvec: enc @ W_gcn[128:144,:] ----------------
__global__ void cvec_kernel(const float* __restrict__ td, const float* __restrict__ mf,
                            const float* __restrict__ Wg, float* __restrict__ cvec) {
    int o = threadIdx.x;
    float t = td[0];
    float acc = 0.f;
#pragma unroll
    for (int j = 0; j < 16; j++) {
        float s = sinf(t * mf[j] * 3.14159265358979323846f);
        acc = fmaf(s, Wg[(128 + j) * C + o], acc);
    }
    cvec[o] = acc;
}

// ---------------- GEMM1: h1 = x @ Wg[0:128,:] + cvec ----------------
__global__ __launch_bounds__(256) void gemm1_kernel(const float* __restrict__ X,
                                                    const float* __restrict__ W,
                                                    const float* __restrict__ cvec,
                                                    float* __restrict__ H) {
    __shared__ __align__(16) float At[32][68];   // x^T chunk: At[k][r]
    __shared__ __align__(16) float Bt[32][68];   // W chunk:  Bt[k][c]
    const int t = threadIdx.x;
    const int r0 = blockIdx.x * 64;
    const int c0 = blockIdx.y * 64;
    const int tr = t >> 4, tc = t & 15;
    float acc[4][4] = {};
    for (int k0 = 0; k0 < 128; k0 += 32) {
#pragma unroll
        for (int rr = 0; rr < 64; rr += 32) {
            int lr = rr + (t >> 3);
            int r = r0 + lr;
            int kk = (t & 7) * 4;
            float4 v = make_float4(0.f, 0.f, 0.f, 0.f);
            if (r < NN) v = *(const float4*)(X + (size_t)r * C + k0 + kk);
            At[kk + 0][lr] = v.x; At[kk + 1][lr] = v.y;
            At[kk + 2][lr] = v.z; At[kk + 3][lr] = v.w;
        }
#pragma unroll
        for (int kk2 = 0; kk2 < 32; kk2 += 16) {
            int k = kk2 + (t >> 4);
            int c = (t & 15) * 4;
            *(float4*)&Bt[k][c] = *(const float4*)(W + (size_t)(k0 + k) * C + c0 + c);
        }
        __syncthreads();
#pragma unroll
        for (int k = 0; k < 32; k++) {
            float4 a = *(const float4*)&At[k][tr * 4];
            float4 b = *(const float4*)&Bt[k][tc * 4];
            float av[4] = {a.x, a.y, a.z, a.w};
            float bv[4] = {b.x, b.y, b.z, b.w};
#pragma unroll
            for (int i = 0; i < 4; i++)
#pragma unroll
                for (int j = 0; j < 4; j++)
                    acc[i][j] = fmaf(av[i], bv[j], acc[i][j]);
        }
        __syncthreads();
    }
    float4 cv = *(const float4*)(cvec + c0 + tc * 4);
#pragma unroll
    for (int i = 0; i < 4; i++) {
        int r = r0 + tr * 4 + i;
        if (r < NN) {
            float4 o;
            o.x = acc[i][0] + cv.x; o.y = acc[i][1] + cv.y;
            o.z = acc[i][2] + cv.z; o.w = acc[i][3] + cv.w;
            *(float4*)(H + (size_t)r * C + c0 + tc * 4) = o;
        }
    }
}

// ---------------- degree ----------------
__global__ void deg_kernel(const int* __restrict__ ei, const float* __restrict__ ew,
                           float* __restrict__ deg) {
    int e = blockIdx.x * blockDim.x + threadIdx.x;
    if (e < NE) atomicAdd(&deg[ei[NE + e]], ew[e]);
}

__global__ void dinv_kernel(float* __restrict__ deg) {
    int i = blockIdx.x * blockDim.x + threadIdx.x;
    if (i < NN) deg[i] = rsqrtf(deg[i] + 1.0f);   // +1 self-loop; always > 0
}

// ---------------- scatter: out[col] += h1[row] * norm ----------------
__global__ __launch_bounds__(256) void scatter_kernel(const int* __restrict__ ei,
                                                      const float* __restrict__ ew,
                                                      const float* __restrict__ dinv,
                                                      const float* __restrict__ H,
                                                      float* __restrict__ OUT) {
    long gt = (long)blockIdx.x * 256 + threadIdx.x;
    long e = gt >> 5;
    if (e >= NE) return;
    int ch = (int)(gt & 31) * 4;
    int r = ei[e], c = ei[NE + e];
    float w = dinv[r] * ew[e] * dinv[c];
    float4 v = *(const float4*)(H + (size_t)r * C + ch);
    float* dst = OUT + (size_t)c * C + ch;
    atomicAdd(dst + 0, v.x * w);
    atomicAdd(dst + 1, v.y * w);
    atomicAdd(dst + 2, v.z * w);
    atomicAdd(dst + 3, v.w * w);
}

// ---------------- self-loop + b_gcn ----------------
__global__ void selfloop_kernel(const float* __restrict__ H, const float* __restrict__ dinv,
                                const float* __restrict__ bg, float* __restrict__ OUT) {
    long i = (long)blockIdx.x * blockDim.x + threadIdx.x;  // float4 index
    if (i >= (long)NN * 32) return;
    int node = (int)(i >> 5);
    int g = (int)(i & 31) * 4;
    float d = dinv[node];
    float w = d * d;
    float4 h = *(const float4*)(H + (size_t)node * C + g);
    float4 b = *(const float4*)(bg + g);
    float4 o = *(float4*)(OUT + (size_t)node * C + g);
    o.x = fmaf(h.x, w, o.x + b.x);
    o.y = fmaf(h.y, w, o.y + b.y);
    o.z = fmaf(h.z, w, o.z + b.z);
    o.w = fmaf(h.w, w, o.w + b.w);
    *(float4*)(OUT + (size_t)node * C + g) = o;
}

// ---------------- BN stats ----------------
__global__ __launch_bounds__(256) void stats_kernel(const float* __restrict__ H,
                                                    float* __restrict__ ssum,
                                                    float* __restrict__ ssq) {
    const int t = threadIdx.x;
    const int g = t & 31;     // channel group of 4
    const int nl = t >> 5;    // node lane 0..7
    float4 s = {0, 0, 0, 0}, q = {0, 0, 0, 0};
    for (long node = (long)blockIdx.x * 8 + nl; node < NN; node += (long)gridDim.x * 8) {
        float4 v = *(const float4*)(H + node * C + g * 4);
        s.x += v.x; s.y += v.y; s.z += v.z; s.w += v.w;
        q.x = fmaf(v.x, v.x, q.x); q.y = fmaf(v.y, v.y, q.y);
        q.z = fmaf(v.z, v.z, q.z); q.w = fmaf(v.w, v.w, q.w);
    }
    __shared__ float red[256][8];
    red[t][0] = s.x; red[t][1] = s.y; red[t][2] = s.z; red[t][3] = s.w;
    red[t][4] = q.x; red[t][5] = q.y; red[t][6] = q.z; red[t][7] = q.w;
    __syncthreads();
    if (t < 32) {
        float rs[4] = {0, 0, 0, 0}, rq[4] = {0, 0, 0, 0};
        for (int j = 0; j < 8; j++) {
            for (int m = 0; m < 4; m++) {
                rs[m] += red[t + 32 * j][m];
                rq[m] += red[t + 32 * j][4 + m];
            }
        }
        for (int m = 0; m < 4; m++) {
            atomicAdd(&ssum[t * 4 + m], rs[m]);
            atomicAdd(&ssq[t * 4 + m], rq[m]);
        }
    }
}

__global__ void bnparam_kernel(const float* __restrict__ ssum, const float* __restrict__ ssq,
                               const float* __restrict__ gm, const float* __restrict__ bt,
                               float* __restrict__ sc, float* __restrict__ sh) {
    int c = threadIdx.x;
    float mean = ssum[c] / (float)NN;
    float var = ssq[c] / (float)NN - mean * mean;
    var = fmaxf(var, 0.f);
    float r = rsqrtf(var + BN_EPS);
    float s = gm[c] * r;
    sc[c] = s;
    sh[c] = bt[c] - mean * s;
}

// ---------------- final: y = lrelu(BN(h)) @ W_lin + b_lin, in-place ----------------
__global__ __launch_bounds__(256) void final_kernel(float* __restrict__ OUT,
                                                    const float* __restrict__ WL,
                                                    const float* __restrict__ bl,
                                                    const float* __restrict__ sc,
                                                    const float* __restrict__ sh) {
    __shared__ __align__(16) float At[32][68];    // lrelu(BN(h))^T chunk
    __shared__ __align__(16) float Bt[32][132];   // W_lin chunk (all 128 cols)
    const int t = threadIdx.x;
    const int r0 = blockIdx.x * 64;
    const int tr = t >> 4, tc = t & 15;
    float acc[4][8] = {};
    for (int k0 = 0; k0 < 128; k0 += 32) {
#pragma unroll
        for (int rr = 0; rr < 64; rr += 32) {
            int lr = rr + (t >> 3);
            int r = r0 + lr;
            int kk = (t & 7) * 4;
            float4 v = make_float4(0.f, 0.f, 0.f, 0.f);
            if (r < NN) v = *(const float4*)(OUT + (size_t)r * C + k0 + kk);
            float4 s4 = *(const float4*)(sc + k0 + kk);
            float4 h4 = *(const float4*)(sh + k0 + kk);
            float a0 = fmaf(v.x, s4.x, h4.x); a0 = a0 >= 0.f ? a0 : NEG * a0;
            float a1 = fmaf(v.y, s4.y, h4.y); a1 = a1 >= 0.f ? a1 : NEG * a1;
            float a2 = fmaf(v.z, s4.z, h4.z); a2 = a2 >= 0.f ? a2 : NEG * a2;
            float a3 = fmaf(v.w, s4.w, h4.w); a3 = a3 >= 0.f ? a3 : NEG * a3;
            At[kk + 0][lr] = a0; At[kk + 1][lr] = a1;
            At[kk + 2][lr] = a2; At[kk + 3][lr] = a3;
        }
#pragma unroll
        for (int kk2 = 0; kk2 < 32; kk2 += 8) {
            int k = kk2 + (t >> 5);
            int c = (t & 31) * 4;
            *(float4*)&Bt[k][c] = *(const float4*)(WL + (size_t)(k0 + k) * C + c);
        }
        __syncthreads();
#pragma unroll
        for (int k = 0; k < 32; k++) {
            float4 a = *(const float4*)&At[k][tr * 4];
            float4 b0 = *(const float4*)&Bt[k][tc * 8];
            float4 b1 = *(const float4*)&Bt[k][tc * 8 + 4];
            float av[4] = {a.x, a.y, a.z, a.w};
            float bv[8] = {b0.x, b0.y, b0.z, b0.w, b1.x, b1.y, b1.z, b1.w};
#pragma unroll
            for (int i = 0; i < 4; i++)
#pragma unroll
                for (int j = 0; j < 8; j++)
                    acc[i][j] = fmaf(av[i], bv[j], acc[i][j]);
        }
        __syncthreads();
    }
    float4 bl0 = *(const float4*)(bl + tc * 8);
    float4 bl1 = *(const float4*)(bl + tc * 8 + 4);
#pragma unroll
    for (int i = 0; i < 4; i++) {
        int r = r0 + tr * 4 + i;
        if (r < NN) {
            float4 o0, o1;
            o0.x = acc[i][0] + bl0.x; o0.y = acc[i][1] + bl0.y;
            o0.z = acc[i][2] + bl0.z; o0.w = acc[i][3] + bl0.w;
            o1.x = acc[i][4] + bl1.x; o1.y = acc[i][5] + bl1.y;
            o1.z = acc[i][6] + bl1.z; o1.w = acc[i][7] + bl1.w;
            *(float4*)(OUT + (size_t)r * C + tc * 8) = o0;
            *(float4*)(OUT + (size_t)r * C + tc * 8 + 4) = o1;
        }
    }
}

extern "C" void kernel_launch(void* const* d_in, const int* in_sizes, int n_in,
                              void* d_out, int out_size, void* d_ws, size_t ws_size,
                              hipStream_t stream) {
    const float* x  = (const float*)d_in[0];
    const int*   ei = (const int*)d_in[1];
    const float* ew = (const float*)d_in[2];
    const float* td = (const float*)d_in[3];
    const float* mf = (const float*)d_in[4];
    const float* Wg = (const float*)d_in[5];
    const float* bg = (const float*)d_in[6];
    const float* gm = (const float*)d_in[7];
    const float* bt = (const float*)d_in[8];
    const float* Wl = (const float*)d_in[9];
    const float* bl = (const float*)d_in[10];
    float* out = (float*)d_out;

    float* h1   = (float*)d_ws;            // NN*C
    float* deg  = h1 + (size_t)NN * C;     // NN (becomes dinv)
    float* cvec = deg + NN;                // C
    float* ssum = cvec + C;                // C
    float* ssq  = ssum + C;                // C
    float* sc   = ssq + C;                 // C
    float* sh   = sc + C;                  // C

    zero_kernel<<<2048, 256, 0, stream>>>(out, (long)NN * C);
    zero_kernel<<<64, 256, 0, stream>>>(deg, NN + 5 * C);
    cvec_kernel<<<1, 128, 0, stream>>>(td, mf, Wg, cvec);
    gemm1_kernel<<<dim3((NN + 63) / 64, 2), 256, 0, stream>>>(x, Wg, cvec, h1);
    deg_kernel<<<(NE + 255) / 256, 256, 0, stream>>>(ei, ew, deg);
    dinv_kernel<<<(NN + 255) / 256, 256, 0, stream>>>(deg);
    scatter_kernel<<<(int)(((long)NE * 32 + 255) / 256), 256, 0, stream>>>(ei, ew, deg, h1, out);
    selfloop_kernel<<<(int)(((long)NN * 32 + 255) / 256), 256, 0, stream>>>(h1, deg, bg, out);
    stats_kernel<<<512, 256, 0, stream>>>(out, ssum, ssq);
    bnparam_kernel<<<1, 128, 0, stream>>>(ssum, ssq, gm, bt, sc, sh);
    final_kernel<<<(NN + 63) / 64, 256, 0, stream>>>(out, Wl, bl, sc, sh);
}

// Round 2
// 356.122 us; speedup vs baseline: 2.8599x; 2.8599x over previous
//
#include <hip/hip_runtime.h>
#include <hip/hip_bf16.h>

#define NN 50000
#define NE 500000
#define C 128
#define BN_EPS 1e-5f
#define NEG 0.01f

// ---------------- zero ----------------
__global__ void zero_kernel(float* __restrict__ p, long n) {
    long i = (long)blockIdx.x * blockDim.x + threadIdx.x;
    long s = (long)gridDim.x * blockDim.x;
    for (; i < n; i += s) p[i] = 0.f;
}

// ---------------- cvec: enc @ W_gcn[128:144,:] ----------------
__global__ void cvec_kernel(const float* __restrict__ td, const float* __restrict__ mf,
                            const float* __restrict__ Wg, float* __restrict__ cvec) {
    int o = threadIdx.x;
    float t = td[0];
    float acc = 0.f;
#pragma unroll
    for (int j = 0; j < 16; j++) {
        float s = sinf(t * mf[j] * 3.14159265358979323846f);
        acc = fmaf(s, Wg[(128 + j) * C + o], acc);
    }
    cvec[o] = acc;
}

// ---------------- GEMM1: h1 = x @ Wg[0:128,:] + cvec ----------------
__global__ __launch_bounds__(256) void gemm1_kernel(const float* __restrict__ X,
                                                    const float* __restrict__ W,
                                                    const float* __restrict__ cvec,
                                                    float* __restrict__ H) {
    __shared__ __align__(16) float At[32][68];   // x^T chunk: At[k][r]
    __shared__ __align__(16) float Bt[32][68];   // W chunk:  Bt[k][c]
    const int t = threadIdx.x;
    const int r0 = blockIdx.x * 64;
    const int c0 = blockIdx.y * 64;
    const int tr = t >> 4, tc = t & 15;
    float acc[4][4] = {};
    for (int k0 = 0; k0 < 128; k0 += 32) {
#pragma unroll
        for (int rr = 0; rr < 64; rr += 32) {
            int lr = rr + (t >> 3);
            int r = r0 + lr;
            int kk = (t & 7) * 4;
            float4 v = make_float4(0.f, 0.f, 0.f, 0.f);
            if (r < NN) v = *(const float4*)(X + (size_t)r * C + k0 + kk);
            At[kk + 0][lr] = v.x; At[kk + 1][lr] = v.y;
            At[kk + 2][lr] = v.z; At[kk + 3][lr] = v.w;
        }
#pragma unroll
        for (int kk2 = 0; kk2 < 32; kk2 += 16) {
            int k = kk2 + (t >> 4);
            int c = (t & 15) * 4;
            *(float4*)&Bt[k][c] = *(const float4*)(W + (size_t)(k0 + k) * C + c0 + c);
        }
        __syncthreads();
#pragma unroll
        for (int k = 0; k < 32; k++) {
            float4 a = *(const float4*)&At[k][tr * 4];
            float4 b = *(const float4*)&Bt[k][tc * 4];
            float av[4] = {a.x, a.y, a.z, a.w};
            float bv[4] = {b.x, b.y, b.z, b.w};
#pragma unroll
            for (int i = 0; i < 4; i++)
#pragma unroll
                for (int j = 0; j < 4; j++)
                    acc[i][j] = fmaf(av[i], bv[j], acc[i][j]);
        }
        __syncthreads();
    }
    float4 cv = *(const float4*)(cvec + c0 + tc * 4);
#pragma unroll
    for (int i = 0; i < 4; i++) {
        int r = r0 + tr * 4 + i;
        if (r < NN) {
            float4 o;
            o.x = acc[i][0] + cv.x; o.y = acc[i][1] + cv.y;
            o.z = acc[i][2] + cv.z; o.w = acc[i][3] + cv.w;
            *(float4*)(H + (size_t)r * C + c0 + tc * 4) = o;
        }
    }
}

// ---------------- histogram: per-dest edge count + weighted degree ----------------
__global__ void hist_kernel(const int* __restrict__ ei, const float* __restrict__ ew,
                            int* __restrict__ cnt, float* __restrict__ deg) {
    int e = blockIdx.x * blockDim.x + threadIdx.x;
    if (e < NE) {
        int c = ei[NE + e];
        atomicAdd(&cnt[c], 1);
        atomicAdd(&deg[c], ew[e]);
    }
}

// ---------------- exclusive prefix scan over cnt -> rptr (single block) ----------------
__global__ __launch_bounds__(1024) void scan_kernel(const int* __restrict__ cnt,
                                                    int* __restrict__ rptr) {
    __shared__ int sums[1024];
    const int t = threadIdx.x;
    const int per = (NN + 1023) / 1024;  // 49
    const int base = t * per;
    int local = 0;
    for (int i = 0; i < per; i++) {
        int idx = base + i;
        if (idx < NN) local += cnt[idx];
    }
    sums[t] = local;
    __syncthreads();
    for (int off = 1; off < 1024; off <<= 1) {
        int add = (t >= off) ? sums[t - off] : 0;
        __syncthreads();
        sums[t] += add;
        __syncthreads();
    }
    int run = (t == 0) ? 0 : sums[t - 1];
    for (int i = 0; i < per; i++) {
        int idx = base + i;
        if (idx < NN) { rptr[idx] = run; run += cnt[idx]; }
    }
    if (t == 1023) rptr[NN] = run;
}

__global__ void dinv_kernel(float* __restrict__ deg) {
    int i = blockIdx.x * blockDim.x + threadIdx.x;
    if (i < NN) deg[i] = rsqrtf(deg[i] + 1.0f);   // +1 self-loop; always > 0
}

// ---------------- fill CSR slots with (src, norm) ----------------
__global__ void fill_kernel(const int* __restrict__ ei, const float* __restrict__ ew,
                            const float* __restrict__ dinv, const int* __restrict__ rptr,
                            int* __restrict__ cursor, int* __restrict__ csr_src,
                            float* __restrict__ csr_w) {
    int e = blockIdx.x * blockDim.x + threadIdx.x;
    if (e >= NE) return;
    int r = ei[e], c = ei[NE + e];
    int slot = rptr[c] + atomicAdd(&cursor[c], 1);
    csr_src[slot] = r;
    csr_w[slot] = dinv[r] * ew[e] * dinv[c];
}

// ---------------- SpMM: out[c] = sum_j norm_j * h1[src_j] + dinv[c]^2*h1[c] + b ----------------
__global__ __launch_bounds__(256) void spmm_kernel(const int* __restrict__ rptr,
                                                   const int* __restrict__ csr_src,
                                                   const float* __restrict__ csr_w,
                                                   const float* __restrict__ H,
                                                   const float* __restrict__ dinv,
                                                   const float* __restrict__ bg,
                                                   float* __restrict__ OUT) {
    int node = blockIdx.x * 4 + (threadIdx.x >> 6);
    if (node >= NN) return;
    int ch = (threadIdx.x & 63) * 2;
    int s = rptr[node], e = rptr[node + 1];
    float d = dinv[node];
    float2 h = *(const float2*)(H + (size_t)node * C + ch);
    float2 acc;
    acc.x = d * d * h.x;
    acc.y = d * d * h.y;
    for (int j = s; j < e; j++) {
        int r = csr_src[j];     // uniform across wave -> broadcast
        float w = csr_w[j];
        float2 v = *(const float2*)(H + (size_t)r * C + ch);
        acc.x = fmaf(v.x, w, acc.x);
        acc.y = fmaf(v.y, w, acc.y);
    }
    float2 b = *(const float2*)(bg + ch);
    acc.x += b.x;
    acc.y += b.y;
    *(float2*)(OUT + (size_t)node * C + ch) = acc;
}

// ---------------- BN stats ----------------
__global__ __launch_bounds__(256) void stats_kernel(const float* __restrict__ H,
                                                    float* __restrict__ ssum,
                                                    float* __restrict__ ssq) {
    const int t = threadIdx.x;
    const int g = t & 31;     // channel group of 4
    const int nl = t >> 5;    // node lane 0..7
    float4 s = {0, 0, 0, 0}, q = {0, 0, 0, 0};
    for (long node = (long)blockIdx.x * 8 + nl; node < NN; node += (long)gridDim.x * 8) {
        float4 v = *(const float4*)(H + node * C + g * 4);
        s.x += v.x; s.y += v.y; s.z += v.z; s.w += v.w;
        q.x = fmaf(v.x, v.x, q.x); q.y = fmaf(v.y, v.y, q.y);
        q.z = fmaf(v.z, v.z, q.z); q.w = fmaf(v.w, v.w, q.w);
    }
    __shared__ float red[256][8];
    red[t][0] = s.x; red[t][1] = s.y; red[t][2] = s.z; red[t][3] = s.w;
    red[t][4] = q.x; red[t][5] = q.y; red[t][6] = q.z; red[t][7] = q.w;
    __syncthreads();
    if (t < 32) {
        float rs[4] = {0, 0, 0, 0}, rq[4] = {0, 0, 0, 0};
        for (int j = 0; j < 8; j++) {
            for (int m = 0; m < 4; m++) {
                rs[m] += red[t + 32 * j][m];
                rq[m] += red[t + 32 * j][4 + m];
            }
        }
        for (int m = 0; m < 4; m++) {
            atomicAdd(&ssum[t * 4 + m], rs[m]);
            atomicAdd(&ssq[t * 4 + m], rq[m]);
        }
    }
}

__global__ void bnparam_kernel(const float* __restrict__ ssum, const float* __restrict__ ssq,
                               const float* __restrict__ gm, const float* __restrict__ bt,
                               float* __restrict__ sc, float* __restrict__ sh) {
    int c = threadIdx.x;
    float mean = ssum[c] / (float)NN;
    float var = ssq[c] / (float)NN - mean * mean;
    var = fmaxf(var, 0.f);
    float r = rsqrtf(var + BN_EPS);
    float s = gm[c] * r;
    sc[c] = s;
    sh[c] = bt[c] - mean * s;
}

// ---------------- final: y = lrelu(BN(h)) @ W_lin + b_lin, in-place ----------------
__global__ __launch_bounds__(256) void final_kernel(float* __restrict__ OUT,
                                                    const float* __restrict__ WL,
                                                    const float* __restrict__ bl,
                                                    const float* __restrict__ sc,
                                                    const float* __restrict__ sh) {
    __shared__ __align__(16) float At[32][68];    // lrelu(BN(h))^T chunk
    __shared__ __align__(16) float Bt[32][132];   // W_lin chunk (all 128 cols)
    const int t = threadIdx.x;
    const int r0 = blockIdx.x * 64;
    const int tr = t >> 4, tc = t & 15;
    float acc[4][8] = {};
    for (int k0 = 0; k0 < 128; k0 += 32) {
#pragma unroll
        for (int rr = 0; rr < 64; rr += 32) {
            int lr = rr + (t >> 3);
            int r = r0 + lr;
            int kk = (t & 7) * 4;
            float4 v = make_float4(0.f, 0.f, 0.f, 0.f);
            if (r < NN) v = *(const float4*)(OUT + (size_t)r * C + k0 + kk);
            float4 s4 = *(const float4*)(sc + k0 + kk);
            float4 h4 = *(const float4*)(sh + k0 + kk);
            float a0 = fmaf(v.x, s4.x, h4.x); a0 = a0 >= 0.f ? a0 : NEG * a0;
            float a1 = fmaf(v.y, s4.y, h4.y); a1 = a1 >= 0.f ? a1 : NEG * a1;
            float a2 = fmaf(v.z, s4.z, h4.z); a2 = a2 >= 0.f ? a2 : NEG * a2;
            float a3 = fmaf(v.w, s4.w, h4.w); a3 = a3 >= 0.f ? a3 : NEG * a3;
            At[kk + 0][lr] = a0; At[kk + 1][lr] = a1;
            At[kk + 2][lr] = a2; At[kk + 3][lr] = a3;
        }
#pragma unroll
        for (int kk2 = 0; kk2 < 32; kk2 += 8) {
            int k = kk2 + (t >> 5);
            int c = (t & 31) * 4;
            *(float4*)&Bt[k][c] = *(const float4*)(WL + (size_t)(k0 + k) * C + c);
        }
        __syncthreads();
#pragma unroll
        for (int k = 0; k < 32; k++) {
            float4 a = *(const float4*)&At[k][tr * 4];
            float4 b0 = *(const float4*)&Bt[k][tc * 8];
            float4 b1 = *(const float4*)&Bt[k][tc * 8 + 4];
            float av[4] = {a.x, a.y, a.z, a.w};
            float bv[8] = {b0.x, b0.y, b0.z, b0.w, b1.x, b1.y, b1.z, b1.w};
#pragma unroll
            for (int i = 0; i < 4; i++)
#pragma unroll
                for (int j = 0; j < 8; j++)
                    acc[i][j] = fmaf(av[i], bv[j], acc[i][j]);
        }
        __syncthreads();
    }
    float4 bl0 = *(const float4*)(bl + tc * 8);
    float4 bl1 = *(const float4*)(bl + tc * 8 + 4);
#pragma unroll
    for (int i = 0; i < 4; i++) {
        int r = r0 + tr * 4 + i;
        if (r < NN) {
            float4 o0, o1;
            o0.x = acc[i][0] + bl0.x; o0.y = acc[i][1] + bl0.y;
            o0.z = acc[i][2] + bl0.z; o0.w = acc[i][3] + bl0.w;
            o1.x = acc[i][4] + bl1.x; o1.y = acc[i][5] + bl1.y;
            o1.z = acc[i][6] + bl1.z; o1.w = acc[i][7] + bl1.w;
            *(float4*)(OUT + (size_t)r * C + tc * 8) = o0;
            *(float4*)(OUT + (size_t)r * C + tc * 8 + 4) = o1;
        }
    }
}

extern "C" void kernel_launch(void* const* d_in, const int* in_sizes, int n_in,
                              void* d_out, int out_size, void* d_ws, size_t ws_size,
                              hipStream_t stream) {
    const float* x  = (const float*)d_in[0];
    const int*   ei = (const int*)d_in[1];
    const float* ew = (const float*)d_in[2];
    const float* td = (const float*)d_in[3];
    const float* mf = (const float*)d_in[4];
    const float* Wg = (const float*)d_in[5];
    const float* bg = (const float*)d_in[6];
    const float* gm = (const float*)d_in[7];
    const float* bt = (const float*)d_in[8];
    const float* Wl = (const float*)d_in[9];
    const float* bl = (const float*)d_in[10];
    float* out = (float*)d_out;

    // workspace layout (zero region must stay contiguous: deg..ssq)
    float* h1     = (float*)d_ws;              // NN*C
    float* deg    = h1 + (size_t)NN * C;       // NN (becomes dinv)
    int*   cnt    = (int*)(deg + NN);          // NN
    int*   cursor = cnt + NN;                  // NN
    float* ssum   = (float*)(cursor + NN);     // C
    float* ssq    = ssum + C;                  // C
    float* cvec   = ssq + C;                   // C
    float* sc     = cvec + C;                  // C
    float* sh     = sc + C;                    // C
    int*   rptr   = (int*)(sh + C);            // NN+1
    int*   csr_src= rptr + NN + 8;             // NE
    float* csr_w  = (float*)(csr_src + NE);    // NE

    zero_kernel<<<64, 256, 0, stream>>>(deg, 3L * NN + 2 * C);
    cvec_kernel<<<1, 128, 0, stream>>>(td, mf, Wg, cvec);
    gemm1_kernel<<<dim3((NN + 63) / 64, 2), 256, 0, stream>>>(x, Wg, cvec, h1);
    hist_kernel<<<(NE + 255) / 256, 256, 0, stream>>>(ei, ew, cnt, deg);
    scan_kernel<<<1, 1024, 0, stream>>>(cnt, rptr);
    dinv_kernel<<<(NN + 255) / 256, 256, 0, stream>>>(deg);
    fill_kernel<<<(NE + 255) / 256, 256, 0, stream>>>(ei, ew, deg, rptr, cursor, csr_src, csr_w);
    spmm_kernel<<<(NN + 3) / 4, 256, 0, stream>>>(rptr, csr_src, csr_w, h1, deg, bg, out);
    stats_kernel<<<512, 256, 0, stream>>>(out, ssum, ssq);
    bnparam_kernel<<<1, 128, 0, stream>>>(ssum, ssq, gm, bt, sc, sh);
    final_kernel<<<(NN + 63) / 64, 256, 0, stream>>>(out, Wl, bl, sc, sh);
}

// Round 3
// 252.266 us; speedup vs baseline: 4.0373x; 1.4117x over previous
//
#include <hip/hip_runtime.h>
#include <hip/hip_bf16.h>

#define NN 50000
#define NE 500000
#define C 128
#define NBLK ((NN + 255) / 256)   // 196
#define BN_EPS 1e-5f
#define NEG 0.01f

// ---------------- zero ----------------
__global__ void zero_kernel(float* __restrict__ p, long n) {
    long i = (long)blockIdx.x * blockDim.x + threadIdx.x;
    long s = (long)gridDim.x * blockDim.x;
    for (; i < n; i += s) p[i] = 0.f;
}

// ---------------- cvec: enc @ W_gcn[128:144,:] ----------------
__global__ void cvec_kernel(const float* __restrict__ td, const float* __restrict__ mf,
                            const float* __restrict__ Wg, float* __restrict__ cvec) {
    int o = threadIdx.x;
    float t = td[0];
    float acc = 0.f;
#pragma unroll
    for (int j = 0; j < 16; j++) {
        float s = sinf(t * mf[j] * 3.14159265358979323846f);
        acc = fmaf(s, Wg[(128 + j) * C + o], acc);
    }
    cvec[o] = acc;
}

// ---------------- GEMM1: h1 = x @ Wg[0:128,:] + cvec ----------------
__global__ __launch_bounds__(256) void gemm1_kernel(const float* __restrict__ X,
                                                    const float* __restrict__ W,
                                                    const float* __restrict__ cvec,
                                                    float* __restrict__ H) {
    __shared__ __align__(16) float At[32][68];   // x^T chunk: At[k][r]
    __shared__ __align__(16) float Bt[32][68];   // W chunk:  Bt[k][c]
    const int t = threadIdx.x;
    const int r0 = blockIdx.x * 64;
    const int c0 = blockIdx.y * 64;
    const int tr = t >> 4, tc = t & 15;
    float acc[4][4] = {};
    for (int k0 = 0; k0 < 128; k0 += 32) {
#pragma unroll
        for (int rr = 0; rr < 64; rr += 32) {
            int lr = rr + (t >> 3);
            int r = r0 + lr;
            int kk = (t & 7) * 4;
            float4 v = make_float4(0.f, 0.f, 0.f, 0.f);
            if (r < NN) v = *(const float4*)(X + (size_t)r * C + k0 + kk);
            At[kk + 0][lr] = v.x; At[kk + 1][lr] = v.y;
            At[kk + 2][lr] = v.z; At[kk + 3][lr] = v.w;
        }
#pragma unroll
        for (int kk2 = 0; kk2 < 32; kk2 += 16) {
            int k = kk2 + (t >> 4);
            int c = (t & 15) * 4;
            *(float4*)&Bt[k][c] = *(const float4*)(W + (size_t)(k0 + k) * C + c0 + c);
        }
        __syncthreads();
#pragma unroll
        for (int k = 0; k < 32; k++) {
            float4 a = *(const float4*)&At[k][tr * 4];
            float4 b = *(const float4*)&Bt[k][tc * 4];
            float av[4] = {a.x, a.y, a.z, a.w};
            float bv[4] = {b.x, b.y, b.z, b.w};
#pragma unroll
            for (int i = 0; i < 4; i++)
#pragma unroll
                for (int j = 0; j < 4; j++)
                    acc[i][j] = fmaf(av[i], bv[j], acc[i][j]);
        }
        __syncthreads();
    }
    float4 cv = *(const float4*)(cvec + c0 + tc * 4);
#pragma unroll
    for (int i = 0; i < 4; i++) {
        int r = r0 + tr * 4 + i;
        if (r < NN) {
            float4 o;
            o.x = acc[i][0] + cv.x; o.y = acc[i][1] + cv.y;
            o.z = acc[i][2] + cv.z; o.w = acc[i][3] + cv.w;
            *(float4*)(H + (size_t)r * C + c0 + tc * 4) = o;
        }
    }
}

// ---------------- histogram: per-dest edge count + weighted degree ----------------
__global__ void hist_kernel(const int* __restrict__ ei, const float* __restrict__ ew,
                            int* __restrict__ cnt, float* __restrict__ deg) {
    int e = blockIdx.x * blockDim.x + threadIdx.x;
    if (e < NE) {
        int c = ei[NE + e];
        atomicAdd(&cnt[c], 1);
        atomicAdd(&deg[c], ew[e]);
    }
}

// ---------------- hierarchical exclusive scan: pass 1 (per-block) ----------------
__global__ __launch_bounds__(256) void scanp1_kernel(const int* __restrict__ cnt,
                                                     int* __restrict__ rptr,
                                                     int* __restrict__ bsum) {
    __shared__ int s[256];
    const int t = threadIdx.x;
    const int i = blockIdx.x * 256 + t;
    int v = (i < NN) ? cnt[i] : 0;
    s[t] = v;
    __syncthreads();
    for (int off = 1; off < 256; off <<= 1) {
        int add = (t >= off) ? s[t - off] : 0;
        __syncthreads();
        s[t] += add;
        __syncthreads();
    }
    if (i < NN) rptr[i] = s[t] - v;           // exclusive within block
    if (t == 255) bsum[blockIdx.x] = s[255];  // block total
}

// ---------------- pass 2: exclusive scan of the 196 block totals ----------------
__global__ __launch_bounds__(256) void scanp2_kernel(const int* __restrict__ bsum,
                                                     int* __restrict__ boff) {
    __shared__ int s[256];
    const int t = threadIdx.x;
    int v = (t < NBLK) ? bsum[t] : 0;
    s[t] = v;
    __syncthreads();
    for (int off = 1; off < 256; off <<= 1) {
        int add = (t >= off) ? s[t - off] : 0;
        __syncthreads();
        s[t] += add;
        __syncthreads();
    }
    if (t < NBLK) boff[t] = s[t] - v;
}

// ---------------- pass 3: add block offsets; fused dinv ----------------
__global__ void scanp3_kernel(int* __restrict__ rptr, const int* __restrict__ boff,
                              float* __restrict__ deg) {
    int i = blockIdx.x * blockDim.x + threadIdx.x;
    if (i < NN) {
        rptr[i] += boff[i >> 8];
        deg[i] = rsqrtf(deg[i] + 1.0f);   // +1 self-loop; always > 0
    }
    if (i == 0) rptr[NN] = NE;            // total is a constant
}

// ---------------- fill CSR slots with (src, norm) ----------------
__global__ void fill_kernel(const int* __restrict__ ei, const float* __restrict__ ew,
                            const float* __restrict__ dinv, const int* __restrict__ rptr,
                            int* __restrict__ cursor, int* __restrict__ csr_src,
                            float* __restrict__ csr_w) {
    int e = blockIdx.x * blockDim.x + threadIdx.x;
    if (e >= NE) return;
    int r = ei[e], c = ei[NE + e];
    int slot = rptr[c] + atomicAdd(&cursor[c], 1);
    csr_src[slot] = r;
    csr_w[slot] = dinv[r] * ew[e] * dinv[c];
}

// ---------------- SpMM: out[c] = sum_j norm_j * h1[src_j] + dinv[c]^2*h1[c] + b ----------------
__global__ __launch_bounds__(256) void spmm_kernel(const int* __restrict__ rptr,
                                                   const int* __restrict__ csr_src,
                                                   const float* __restrict__ csr_w,
                                                   const float* __restrict__ H,
                                                   const float* __restrict__ dinv,
                                                   const float* __restrict__ bg,
                                                   float* __restrict__ OUT) {
    int node = blockIdx.x * 8 + (threadIdx.x >> 5);   // half-wave per node
    if (node >= NN) return;
    int ch = (threadIdx.x & 31) * 4;                  // 32 lanes x float4 = 128 ch
    int s = rptr[node], e = rptr[node + 1];
    float d = dinv[node];
    float dd = d * d;
    float4 h = *(const float4*)(H + (size_t)node * C + ch);
    float4 acc = make_float4(dd * h.x, dd * h.y, dd * h.z, dd * h.w);
    int j = s;
    for (; j + 2 <= e; j += 2) {
        int r0 = csr_src[j], r1 = csr_src[j + 1];
        float w0 = csr_w[j], w1 = csr_w[j + 1];
        float4 v0 = *(const float4*)(H + (size_t)r0 * C + ch);
        float4 v1 = *(const float4*)(H + (size_t)r1 * C + ch);
        acc.x = fmaf(v0.x, w0, acc.x); acc.y = fmaf(v0.y, w0, acc.y);
        acc.z = fmaf(v0.z, w0, acc.z); acc.w = fmaf(v0.w, w0, acc.w);
        acc.x = fmaf(v1.x, w1, acc.x); acc.y = fmaf(v1.y, w1, acc.y);
        acc.z = fmaf(v1.z, w1, acc.z); acc.w = fmaf(v1.w, w1, acc.w);
    }
    if (j < e) {
        int r0 = csr_src[j];
        float w0 = csr_w[j];
        float4 v0 = *(const float4*)(H + (size_t)r0 * C + ch);
        acc.x = fmaf(v0.x, w0, acc.x); acc.y = fmaf(v0.y, w0, acc.y);
        acc.z = fmaf(v0.z, w0, acc.z); acc.w = fmaf(v0.w, w0, acc.w);
    }
    float4 b = *(const float4*)(bg + ch);
    acc.x += b.x; acc.y += b.y; acc.z += b.z; acc.w += b.w;
    *(float4*)(OUT + (size_t)node * C + ch) = acc;
}

// ---------------- BN stats ----------------
__global__ __launch_bounds__(256) void stats_kernel(const float* __restrict__ H,
                                                    float* __restrict__ ssum,
                                                    float* __restrict__ ssq) {
    const int t = threadIdx.x;
    const int g = t & 31;     // channel group of 4
    const int nl = t >> 5;    // node lane 0..7
    float4 s = {0, 0, 0, 0}, q = {0, 0, 0, 0};
    for (long node = (long)blockIdx.x * 8 + nl; node < NN; node += (long)gridDim.x * 8) {
        float4 v = *(const float4*)(H + node * C + g * 4);
        s.x += v.x; s.y += v.y; s.z += v.z; s.w += v.w;
        q.x = fmaf(v.x, v.x, q.x); q.y = fmaf(v.y, v.y, q.y);
        q.z = fmaf(v.z, v.z, q.z); q.w = fmaf(v.w, v.w, q.w);
    }
    __shared__ float red[256][8];
    red[t][0] = s.x; red[t][1] = s.y; red[t][2] = s.z; red[t][3] = s.w;
    red[t][4] = q.x; red[t][5] = q.y; red[t][6] = q.z; red[t][7] = q.w;
    __syncthreads();
    if (t < 32) {
        float rs[4] = {0, 0, 0, 0}, rq[4] = {0, 0, 0, 0};
        for (int j = 0; j < 8; j++) {
            for (int m = 0; m < 4; m++) {
                rs[m] += red[t + 32 * j][m];
                rq[m] += red[t + 32 * j][4 + m];
            }
        }
        for (int m = 0; m < 4; m++) {
            atomicAdd(&ssum[t * 4 + m], rs[m]);
            atomicAdd(&ssq[t * 4 + m], rq[m]);
        }
    }
}

__global__ void bnparam_kernel(const float* __restrict__ ssum, const float* __restrict__ ssq,
                               const float* __restrict__ gm, const float* __restrict__ bt,
                               float* __restrict__ sc, float* __restrict__ sh) {
    int c = threadIdx.x;
    float mean = ssum[c] / (float)NN;
    float var = ssq[c] / (float)NN - mean * mean;
    var = fmaxf(var, 0.f);
    float r = rsqrtf(var + BN_EPS);
    float s = gm[c] * r;
    sc[c] = s;
    sh[c] = bt[c] - mean * s;
}

// ---------------- final: y = lrelu(BN(h)) @ W_lin + b_lin, in-place ----------------
__global__ __launch_bounds__(256) void final_kernel(float* __restrict__ OUT,
                                                    const float* __restrict__ WL,
                                                    const float* __restrict__ bl,
                                                    const float* __restrict__ sc,
                                                    const float* __restrict__ sh) {
    __shared__ __align__(16) float At[32][68];    // lrelu(BN(h))^T chunk
    __shared__ __align__(16) float Bt[32][132];   // W_lin chunk (all 128 cols)
    const int t = threadIdx.x;
    const int r0 = blockIdx.x * 64;
    const int tr = t >> 4, tc = t & 15;
    float acc[4][8] = {};
    for (int k0 = 0; k0 < 128; k0 += 32) {
#pragma unroll
        for (int rr = 0; rr < 64; rr += 32) {
            int lr = rr + (t >> 3);
            int r = r0 + lr;
            int kk = (t & 7) * 4;
            float4 v = make_float4(0.f, 0.f, 0.f, 0.f);
            if (r < NN) v = *(const float4*)(OUT + (size_t)r * C + k0 + kk);
            float4 s4 = *(const float4*)(sc + k0 + kk);
            float4 h4 = *(const float4*)(sh + k0 + kk);
            float a0 = fmaf(v.x, s4.x, h4.x); a0 = a0 >= 0.f ? a0 : NEG * a0;
            float a1 = fmaf(v.y, s4.y, h4.y); a1 = a1 >= 0.f ? a1 : NEG * a1;
            float a2 = fmaf(v.z, s4.z, h4.z); a2 = a2 >= 0.f ? a2 : NEG * a2;
            float a3 = fmaf(v.w, s4.w, h4.w); a3 = a3 >= 0.f ? a3 : NEG * a3;
            At[kk + 0][lr] = a0; At[kk + 1][lr] = a1;
            At[kk + 2][lr] = a2; At[kk + 3][lr] = a3;
        }
#pragma unroll
        for (int kk2 = 0; kk2 < 32; kk2 += 8) {
            int k = kk2 + (t >> 5);
            int c = (t & 31) * 4;
            *(float4*)&Bt[k][c] = *(const float4*)(WL + (size_t)(k0 + k) * C + c);
        }
        __syncthreads();
#pragma unroll
        for (int k = 0; k < 32; k++) {
            float4 a = *(const float4*)&At[k][tr * 4];
            float4 b0 = *(const float4*)&Bt[k][tc * 8];
            float4 b1 = *(const float4*)&Bt[k][tc * 8 + 4];
            float av[4] = {a.x, a.y, a.z, a.w};
            float bv[8] = {b0.x, b0.y, b0.z, b0.w, b1.x, b1.y, b1.z, b1.w};
#pragma unroll
            for (int i = 0; i < 4; i++)
#pragma unroll
                for (int j = 0; j < 8; j++)
                    acc[i][j] = fmaf(av[i], bv[j], acc[i][j]);
        }
        __syncthreads();
    }
    float4 bl0 = *(const float4*)(bl + tc * 8);
    float4 bl1 = *(const float4*)(bl + tc * 8 + 4);
#pragma unroll
    for (int i = 0; i < 4; i++) {
        int r = r0 + tr * 4 + i;
        if (r < NN) {
            float4 o0, o1;
            o0.x = acc[i][0] + bl0.x; o0.y = acc[i][1] + bl0.y;
            o0.z = acc[i][2] + bl0.z; o0.w = acc[i][3] + bl0.w;
            o1.x = acc[i][4] + bl1.x; o1.y = acc[i][5] + bl1.y;
            o1.z = acc[i][6] + bl1.z; o1.w = acc[i][7] + bl1.w;
            *(float4*)(OUT + (size_t)r * C + tc * 8) = o0;
            *(float4*)(OUT + (size_t)r * C + tc * 8 + 4) = o1;
        }
    }
}

extern "C" void kernel_launch(void* const* d_in, const int* in_sizes, int n_in,
                              void* d_out, int out_size, void* d_ws, size_t ws_size,
                              hipStream_t stream) {
    const float* x  = (const float*)d_in[0];
    const int*   ei = (const int*)d_in[1];
    const float* ew = (const float*)d_in[2];
    const float* td = (const float*)d_in[3];
    const float* mf = (const float*)d_in[4];
    const float* Wg = (const float*)d_in[5];
    const float* bg = (const float*)d_in[6];
    const float* gm = (const float*)d_in[7];
    const float* bt = (const float*)d_in[8];
    const float* Wl = (const float*)d_in[9];
    const float* bl = (const float*)d_in[10];
    float* out = (float*)d_out;

    // workspace layout (zero region must stay contiguous: deg..ssq)
    float* h1     = (float*)d_ws;              // NN*C
    float* deg    = h1 + (size_t)NN * C;       // NN (becomes dinv)
    int*   cnt    = (int*)(deg + NN);          // NN
    int*   cursor = cnt + NN;                  // NN
    float* ssum   = (float*)(cursor + NN);     // C
    float* ssq    = ssum + C;                  // C
    float* cvec   = ssq + C;                   // C
    float* sc     = cvec + C;                  // C
    float* sh     = sc + C;                    // C
    int*   rptr   = (int*)(sh + C);            // NN+1
    int*   bsum   = rptr + NN + 8;             // NBLK
    int*   boff   = bsum + NBLK;               // NBLK
    int*   csr_src= boff + NBLK + 8;           // NE
    float* csr_w  = (float*)(csr_src + NE);    // NE

    zero_kernel<<<256, 256, 0, stream>>>(deg, 3L * NN + 2 * C);
    cvec_kernel<<<1, 128, 0, stream>>>(td, mf, Wg, cvec);
    gemm1_kernel<<<dim3((NN + 63) / 64, 2), 256, 0, stream>>>(x, Wg, cvec, h1);
    hist_kernel<<<(NE + 255) / 256, 256, 0, stream>>>(ei, ew, cnt, deg);
    scanp1_kernel<<<NBLK, 256, 0, stream>>>(cnt, rptr, bsum);
    scanp2_kernel<<<1, 256, 0, stream>>>(bsum, boff);
    scanp3_kernel<<<NBLK, 256, 0, stream>>>(rptr, boff, deg);
    fill_kernel<<<(NE + 255) / 256, 256, 0, stream>>>(ei, ew, deg, rptr, cursor, csr_src, csr_w);
    spmm_kernel<<<(NN + 7) / 8, 256, 0, stream>>>(rptr, csr_src, csr_w, h1, deg, bg, out);
    stats_kernel<<<512, 256, 0, stream>>>(out, ssum, ssq);
    bnparam_kernel<<<1, 128, 0, stream>>>(ssum, ssq, gm, bt, sc, sh);
    final_kernel<<<(NN + 63) / 64, 256, 0, stream>>>(out, Wl, bl, sc, sh);
}

// Round 4
// 207.340 us; speedup vs baseline: 4.9121x; 1.2167x over previous
//
#include <hip/hip_runtime.h>
#include <hip/hip_bf16.h>

#define NN 50000
#define NE 500000
#define C 128
#define NBLK ((NN + 255) / 256)       // 196 scan blocks
#define SPB (NN / 8)                  // 6250 spmm blocks (exact: 50000 = 6250*8)
#define RB 128                        // reduce1 blocks
#define RROWS ((SPB + RB - 1) / RB)   // 49 rows per reduce1 block
#define BN_EPS 1e-5f
#define NEG 0.01f

// ---------------- zero ----------------
__global__ void zero_kernel(float* __restrict__ p, long n) {
    long i = (long)blockIdx.x * blockDim.x + threadIdx.x;
    long s = (long)gridDim.x * blockDim.x;
    for (; i < n; i += s) p[i] = 0.f;
}

// ---------------- cvec: enc @ W_gcn[128:144,:] ----------------
__global__ void cvec_kernel(const float* __restrict__ td, const float* __restrict__ mf,
                            const float* __restrict__ Wg, float* __restrict__ cvec) {
    int o = threadIdx.x;
    float t = td[0];
    float acc = 0.f;
#pragma unroll
    for (int j = 0; j < 16; j++) {
        float s = sinf(t * mf[j] * 3.14159265358979323846f);
        acc = fmaf(s, Wg[(128 + j) * C + o], acc);
    }
    cvec[o] = acc;
}

// ---------------- GEMM1: h1 = x @ Wg[0:128,:] + cvec ----------------
__global__ __launch_bounds__(256) void gemm1_kernel(const float* __restrict__ X,
                                                    const float* __restrict__ W,
                                                    const float* __restrict__ cvec,
                                                    float* __restrict__ H) {
    __shared__ __align__(16) float At[32][68];   // x^T chunk: At[k][r]
    __shared__ __align__(16) float Bt[32][68];   // W chunk:  Bt[k][c]
    const int t = threadIdx.x;
    const int r0 = blockIdx.x * 64;
    const int c0 = blockIdx.y * 64;
    const int tr = t >> 4, tc = t & 15;
    float acc[4][4] = {};
    for (int k0 = 0; k0 < 128; k0 += 32) {
#pragma unroll
        for (int rr = 0; rr < 64; rr += 32) {
            int lr = rr + (t >> 3);
            int r = r0 + lr;
            int kk = (t & 7) * 4;
            float4 v = make_float4(0.f, 0.f, 0.f, 0.f);
            if (r < NN) v = *(const float4*)(X + (size_t)r * C + k0 + kk);
            At[kk + 0][lr] = v.x; At[kk + 1][lr] = v.y;
            At[kk + 2][lr] = v.z; At[kk + 3][lr] = v.w;
        }
#pragma unroll
        for (int kk2 = 0; kk2 < 32; kk2 += 16) {
            int k = kk2 + (t >> 4);
            int c = (t & 15) * 4;
            *(float4*)&Bt[k][c] = *(const float4*)(W + (size_t)(k0 + k) * C + c0 + c);
        }
        __syncthreads();
#pragma unroll
        for (int k = 0; k < 32; k++) {
            float4 a = *(const float4*)&At[k][tr * 4];
            float4 b = *(const float4*)&Bt[k][tc * 4];
            float av[4] = {a.x, a.y, a.z, a.w};
            float bv[4] = {b.x, b.y, b.z, b.w};
#pragma unroll
            for (int i = 0; i < 4; i++)
#pragma unroll
                for (int j = 0; j < 4; j++)
                    acc[i][j] = fmaf(av[i], bv[j], acc[i][j]);
        }
        __syncthreads();
    }
    float4 cv = *(const float4*)(cvec + c0 + tc * 4);
#pragma unroll
    for (int i = 0; i < 4; i++) {
        int r = r0 + tr * 4 + i;
        if (r < NN) {
            float4 o;
            o.x = acc[i][0] + cv.x; o.y = acc[i][1] + cv.y;
            o.z = acc[i][2] + cv.z; o.w = acc[i][3] + cv.w;
            *(float4*)(H + (size_t)r * C + c0 + tc * 4) = o;
        }
    }
}

// ---------------- histogram: per-dest edge count + weighted degree ----------------
__global__ void hist_kernel(const int* __restrict__ ei, const float* __restrict__ ew,
                            int* __restrict__ cnt, float* __restrict__ deg) {
    int e = blockIdx.x * blockDim.x + threadIdx.x;
    if (e < NE) {
        int c = ei[NE + e];
        atomicAdd(&cnt[c], 1);
        atomicAdd(&deg[c], ew[e]);
    }
}

// ---------------- hierarchical exclusive scan: pass 1 (per-block) ----------------
__global__ __launch_bounds__(256) void scanp1_kernel(const int* __restrict__ cnt,
                                                     int* __restrict__ rptr,
                                                     int* __restrict__ bsum) {
    __shared__ int s[256];
    const int t = threadIdx.x;
    const int i = blockIdx.x * 256 + t;
    int v = (i < NN) ? cnt[i] : 0;
    s[t] = v;
    __syncthreads();
    for (int off = 1; off < 256; off <<= 1) {
        int add = (t >= off) ? s[t - off] : 0;
        __syncthreads();
        s[t] += add;
        __syncthreads();
    }
    if (i < NN) rptr[i] = s[t] - v;           // exclusive within block
    if (t == 255) bsum[blockIdx.x] = s[255];  // block total
}

// ---------------- pass 2: exclusive scan of the 196 block totals ----------------
__global__ __launch_bounds__(256) void scanp2_kernel(const int* __restrict__ bsum,
                                                     int* __restrict__ boff) {
    __shared__ int s[256];
    const int t = threadIdx.x;
    int v = (t < NBLK) ? bsum[t] : 0;
    s[t] = v;
    __syncthreads();
    for (int off = 1; off < 256; off <<= 1) {
        int add = (t >= off) ? s[t - off] : 0;
        __syncthreads();
        s[t] += add;
        __syncthreads();
    }
    if (t < NBLK) boff[t] = s[t] - v;
}

// ---------------- pass 3: add block offsets; fused dinv ----------------
__global__ void scanp3_kernel(int* __restrict__ rptr, const int* __restrict__ boff,
                              float* __restrict__ deg) {
    int i = blockIdx.x * blockDim.x + threadIdx.x;
    if (i < NN) {
        rptr[i] += boff[i >> 8];
        deg[i] = rsqrtf(deg[i] + 1.0f);   // +1 self-loop; always > 0
    }
    if (i == 0) rptr[NN] = NE;            // total is a constant
}

// ---------------- fill CSR slots with (src, norm) ----------------
__global__ void fill_kernel(const int* __restrict__ ei, const float* __restrict__ ew,
                            const float* __restrict__ dinv, const int* __restrict__ rptr,
                            int* __restrict__ cursor, int* __restrict__ csr_src,
                            float* __restrict__ csr_w) {
    int e = blockIdx.x * blockDim.x + threadIdx.x;
    if (e >= NE) return;
    int r = ei[e], c = ei[NE + e];
    int slot = rptr[c] + atomicAdd(&cursor[c], 1);
    csr_src[slot] = r;
    csr_w[slot] = dinv[r] * ew[e] * dinv[c];
}

// ---------------- SpMM + fused BN partial stats ----------------
// out[c] = sum_j norm_j * h1[src_j] + dinv[c]^2*h1[c] + b
// P[blk][0:128]   = per-block channel sums of out rows
// P[blk][128:256] = per-block channel sums of out^2
__global__ __launch_bounds__(256) void spmm_kernel(const int* __restrict__ rptr,
                                                   const int* __restrict__ csr_src,
                                                   const float* __restrict__ csr_w,
                                                   const float* __restrict__ H,
                                                   const float* __restrict__ dinv,
                                                   const float* __restrict__ bg,
                                                   float* __restrict__ OUT,
                                                   float* __restrict__ P) {
    const int nl = threadIdx.x >> 5;                 // node lane 0..7
    const int lane = threadIdx.x & 31;               // channel-group lane
    const int node = blockIdx.x * 8 + nl;            // NN == gridDim*8 exactly
    const int ch = lane * 4;
    int s = rptr[node], e = rptr[node + 1];
    float d = dinv[node];
    float dd = d * d;
    float4 h = *(const float4*)(H + (size_t)node * C + ch);
    float4 acc = make_float4(dd * h.x, dd * h.y, dd * h.z, dd * h.w);
    int j = s;
    for (; j + 2 <= e; j += 2) {
        int r0 = csr_src[j], r1 = csr_src[j + 1];
        float w0 = csr_w[j], w1 = csr_w[j + 1];
        float4 v0 = *(const float4*)(H + (size_t)r0 * C + ch);
        float4 v1 = *(const float4*)(H + (size_t)r1 * C + ch);
        acc.x = fmaf(v0.x, w0, acc.x); acc.y = fmaf(v0.y, w0, acc.y);
        acc.z = fmaf(v0.z, w0, acc.z); acc.w = fmaf(v0.w, w0, acc.w);
        acc.x = fmaf(v1.x, w1, acc.x); acc.y = fmaf(v1.y, w1, acc.y);
        acc.z = fmaf(v1.z, w1, acc.z); acc.w = fmaf(v1.w, w1, acc.w);
    }
    if (j < e) {
        int r0 = csr_src[j];
        float w0 = csr_w[j];
        float4 v0 = *(const float4*)(H + (size_t)r0 * C + ch);
        acc.x = fmaf(v0.x, w0, acc.x); acc.y = fmaf(v0.y, w0, acc.y);
        acc.z = fmaf(v0.z, w0, acc.z); acc.w = fmaf(v0.w, w0, acc.w);
    }
    float4 b = *(const float4*)(bg + ch);
    acc.x += b.x; acc.y += b.y; acc.z += b.z; acc.w += b.w;
    *(float4*)(OUT + (size_t)node * C + ch) = acc;

    // ---- fused BN partials: reduce over the block's 8 nodes, no atomics ----
    __shared__ __align__(16) float4 sred[2][8][32];   // 8 KiB
    float4 sq = make_float4(acc.x * acc.x, acc.y * acc.y, acc.z * acc.z, acc.w * acc.w);
    sred[0][nl][lane] = acc;
    sred[1][nl][lane] = sq;
    __syncthreads();
    if (nl == 0) {
        float4 s0 = sred[0][0][lane], q0 = sred[1][0][lane];
#pragma unroll
        for (int k = 1; k < 8; k++) {
            float4 a = sred[0][k][lane];
            float4 q = sred[1][k][lane];
            s0.x += a.x; s0.y += a.y; s0.z += a.z; s0.w += a.w;
            q0.x += q.x; q0.y += q.y; q0.z += q.z; q0.w += q.w;
        }
        float* row = P + (size_t)blockIdx.x * 256;
        *(float4*)(row + ch) = s0;
        *(float4*)(row + 128 + ch) = q0;
    }
}

// ---------------- reduce spmm-block partials: P[6250][256] -> P2[128][256] ----------------
__global__ __launch_bounds__(256) void reduce1_kernel(const float* __restrict__ P,
                                                      float* __restrict__ P2) {
    const int c = threadIdx.x;
    const int r0 = blockIdx.x * RROWS;
    const int r1 = min(r0 + RROWS, SPB);
    float a0 = 0.f, a1 = 0.f, a2 = 0.f, a3 = 0.f;
    int r = r0;
    for (; r + 4 <= r1; r += 4) {
        a0 += P[(size_t)(r + 0) * 256 + c];
        a1 += P[(size_t)(r + 1) * 256 + c];
        a2 += P[(size_t)(r + 2) * 256 + c];
        a3 += P[(size_t)(r + 3) * 256 + c];
    }
    for (; r < r1; r++) a0 += P[(size_t)r * 256 + c];
    P2[(size_t)blockIdx.x * 256 + c] = (a0 + a1) + (a2 + a3);
}

// ---------------- BN params from P2 ----------------
__global__ void bnparam_kernel(const float* __restrict__ P2,
                               const float* __restrict__ gm, const float* __restrict__ bt,
                               float* __restrict__ sc, float* __restrict__ sh) {
    int c = threadIdx.x;   // 0..127
    float s0 = 0.f, s1 = 0.f, q0 = 0.f, q1 = 0.f;
    for (int k = 0; k < RB; k += 2) {
        s0 += P2[(size_t)k * 256 + c];
        q0 += P2[(size_t)k * 256 + 128 + c];
        s1 += P2[(size_t)(k + 1) * 256 + c];
        q1 += P2[(size_t)(k + 1) * 256 + 128 + c];
    }
    float ssum = s0 + s1, ssq = q0 + q1;
    float mean = ssum / (float)NN;
    float var = ssq / (float)NN - mean * mean;
    var = fmaxf(var, 0.f);
    float r = rsqrtf(var + BN_EPS);
    float s = gm[c] * r;
    sc[c] = s;
    sh[c] = bt[c] - mean * s;
}

// ---------------- final: y = lrelu(BN(h)) @ W_lin + b_lin, in-place ----------------
__global__ __launch_bounds__(256) void final_kernel(float* __restrict__ OUT,
                                                    const float* __restrict__ WL,
                                                    const float* __restrict__ bl,
                                                    const float* __restrict__ sc,
                                                    const float* __restrict__ sh) {
    __shared__ __align__(16) float At[32][68];    // lrelu(BN(h))^T chunk
    __shared__ __align__(16) float Bt[32][132];   // W_lin chunk (all 128 cols)
    const int t = threadIdx.x;
    const int r0 = blockIdx.x * 64;
    const int tr = t >> 4, tc = t & 15;
    float acc[4][8] = {};
    for (int k0 = 0; k0 < 128; k0 += 32) {
#pragma unroll
        for (int rr = 0; rr < 64; rr += 32) {
            int lr = rr + (t >> 3);
            int r = r0 + lr;
            int kk = (t & 7) * 4;
            float4 v = make_float4(0.f, 0.f, 0.f, 0.f);
            if (r < NN) v = *(const float4*)(OUT + (size_t)r * C + k0 + kk);
            float4 s4 = *(const float4*)(sc + k0 + kk);
            float4 h4 = *(const float4*)(sh + k0 + kk);
            float a0 = fmaf(v.x, s4.x, h4.x); a0 = a0 >= 0.f ? a0 : NEG * a0;
            float a1 = fmaf(v.y, s4.y, h4.y); a1 = a1 >= 0.f ? a1 : NEG * a1;
            float a2 = fmaf(v.z, s4.z, h4.z); a2 = a2 >= 0.f ? a2 : NEG * a2;
            float a3 = fmaf(v.w, s4.w, h4.w); a3 = a3 >= 0.f ? a3 : NEG * a3;
            At[kk + 0][lr] = a0; At[kk + 1][lr] = a1;
            At[kk + 2][lr] = a2; At[kk + 3][lr] = a3;
        }
#pragma unroll
        for (int kk2 = 0; kk2 < 32; kk2 += 8) {
            int k = kk2 + (t >> 5);
            int c = (t & 31) * 4;
            *(float4*)&Bt[k][c] = *(const float4*)(WL + (size_t)(k0 + k) * C + c);
        }
        __syncthreads();
#pragma unroll
        for (int k = 0; k < 32; k++) {
            float4 a = *(const float4*)&At[k][tr * 4];
            float4 b0 = *(const float4*)&Bt[k][tc * 8];
            float4 b1 = *(const float4*)&Bt[k][tc * 8 + 4];
            float av[4] = {a.x, a.y, a.z, a.w};
            float bv[8] = {b0.x, b0.y, b0.z, b0.w, b1.x, b1.y, b1.z, b1.w};
#pragma unroll
            for (int i = 0; i < 4; i++)
#pragma unroll
                for (int j = 0; j < 8; j++)
                    acc[i][j] = fmaf(av[i], bv[j], acc[i][j]);
        }
        __syncthreads();
    }
    float4 bl0 = *(const float4*)(bl + tc * 8);
    float4 bl1 = *(const float4*)(bl + tc * 8 + 4);
#pragma unroll
    for (int i = 0; i < 4; i++) {
        int r = r0 + tr * 4 + i;
        if (r < NN) {
            float4 o0, o1;
            o0.x = acc[i][0] + bl0.x; o0.y = acc[i][1] + bl0.y;
            o0.z = acc[i][2] + bl0.z; o0.w = acc[i][3] + bl0.w;
            o1.x = acc[i][4] + bl1.x; o1.y = acc[i][5] + bl1.y;
            o1.z = acc[i][6] + bl1.z; o1.w = acc[i][7] + bl1.w;
            *(float4*)(OUT + (size_t)r * C + tc * 8) = o0;
            *(float4*)(OUT + (size_t)r * C + tc * 8 + 4) = o1;
        }
    }
}

extern "C" void kernel_launch(void* const* d_in, const int* in_sizes, int n_in,
                              void* d_out, int out_size, void* d_ws, size_t ws_size,
                              hipStream_t stream) {
    const float* x  = (const float*)d_in[0];
    const int*   ei = (const int*)d_in[1];
    const float* ew = (const float*)d_in[2];
    const float* td = (const float*)d_in[3];
    const float* mf = (const float*)d_in[4];
    const float* Wg = (const float*)d_in[5];
    const float* bg = (const float*)d_in[6];
    const float* gm = (const float*)d_in[7];
    const float* bt = (const float*)d_in[8];
    const float* Wl = (const float*)d_in[9];
    const float* bl = (const float*)d_in[10];
    float* out = (float*)d_out;

    // workspace layout (zero region must stay contiguous: deg..cursor)
    float* h1     = (float*)d_ws;              // NN*C
    float* deg    = h1 + (size_t)NN * C;       // NN (becomes dinv)
    int*   cnt    = (int*)(deg + NN);          // NN
    int*   cursor = cnt + NN;                  // NN
    float* cvec   = (float*)(cursor + NN);     // C
    float* sc     = cvec + C;                  // C
    float* sh     = sc + C;                    // C
    int*   rptr   = (int*)(sh + C);            // NN+1
    int*   bsum   = rptr + NN + 8;             // NBLK
    int*   boff   = bsum + NBLK;               // NBLK
    int*   csr_src= boff + NBLK + 8;           // NE
    float* csr_w  = (float*)(csr_src + NE);    // NE
    float* P      = csr_w + NE;                // SPB*256 (6.4 MB)
    float* P2     = P + (size_t)SPB * 256;     // RB*256

    zero_kernel<<<256, 256, 0, stream>>>(deg, 3L * NN);
    cvec_kernel<<<1, 128, 0, stream>>>(td, mf, Wg, cvec);
    gemm1_kernel<<<dim3((NN + 63) / 64, 2), 256, 0, stream>>>(x, Wg, cvec, h1);
    hist_kernel<<<(NE + 255) / 256, 256, 0, stream>>>(ei, ew, cnt, deg);
    scanp1_kernel<<<NBLK, 256, 0, stream>>>(cnt, rptr, bsum);
    scanp2_kernel<<<1, 256, 0, stream>>>(bsum, boff);
    scanp3_kernel<<<NBLK, 256, 0, stream>>>(rptr, boff, deg);
    fill_kernel<<<(NE + 255) / 256, 256, 0, stream>>>(ei, ew, deg, rptr, cursor, csr_src, csr_w);
    spmm_kernel<<<SPB, 256, 0, stream>>>(rptr, csr_src, csr_w, h1, deg, bg, out, P);
    reduce1_kernel<<<RB, 256, 0, stream>>>(P, P2);
    bnparam_kernel<<<1, 128, 0, stream>>>(P2, gm, bt, sc, sh);
    final_kernel<<<(NN + 63) / 64, 256, 0, stream>>>(out, Wl, bl, sc, sh);
}

// Round 5
// 184.913 us; speedup vs baseline: 5.5079x; 1.1213x over previous
//
#include <hip/hip_runtime.h>
#include <hip/hip_bf16.h>

#define NN 50000
#define NE 500000
#define C 128
#define NBLK ((NN + 255) / 256)       // 196 scan blocks
#define SPB (NN / 8)                  // 6250 spmm blocks (exact: 50000 = 6250*8)
#define RB 128                        // reduce1 blocks
#define RROWS ((SPB + RB - 1) / RB)   // 49 rows per reduce1 block
#define BN_EPS 1e-5f
#define NEG 0.01f
#define WSCALE 16777216.0f            // 2^24 fixed-point for packed degree
#define WMASK  0xFFFFFFFFFFFULL      // low 44 bits

// ---------------- zero ----------------
__global__ void zero_kernel(float* __restrict__ p, long n) {
    long i = (long)blockIdx.x * blockDim.x + threadIdx.x;
    long s = (long)gridDim.x * blockDim.x;
    for (; i < n; i += s) p[i] = 0.f;
}

// ---------------- cvec: enc @ W_gcn[128:144,:] ----------------
__global__ void cvec_kernel(const float* __restrict__ td, const float* __restrict__ mf,
                            const float* __restrict__ Wg, float* __restrict__ cvec) {
    int o = threadIdx.x;
    float t = td[0];
    float acc = 0.f;
#pragma unroll
    for (int j = 0; j < 16; j++) {
        float s = sinf(t * mf[j] * 3.14159265358979323846f);
        acc = fmaf(s, Wg[(128 + j) * C + o], acc);
    }
    cvec[o] = acc;
}

// ---------------- GEMM1: h1 = x @ Wg[0:128,:] + cvec ----------------
__global__ __launch_bounds__(256) void gemm1_kernel(const float* __restrict__ X,
                                                    const float* __restrict__ W,
                                                    const float* __restrict__ cvec,
                                                    float* __restrict__ H) {
    __shared__ __align__(16) float At[32][68];   // x^T chunk: At[k][r]
    __shared__ __align__(16) float Bt[32][68];   // W chunk:  Bt[k][c]
    const int t = threadIdx.x;
    const int r0 = blockIdx.x * 64;
    const int c0 = blockIdx.y * 64;
    const int tr = t >> 4, tc = t & 15;
    float acc[4][4] = {};
    for (int k0 = 0; k0 < 128; k0 += 32) {
#pragma unroll
        for (int rr = 0; rr < 64; rr += 32) {
            int lr = rr + (t >> 3);
            int r = r0 + lr;
            int kk = (t & 7) * 4;
            float4 v = make_float4(0.f, 0.f, 0.f, 0.f);
            if (r < NN) v = *(const float4*)(X + (size_t)r * C + k0 + kk);
            At[kk + 0][lr] = v.x; At[kk + 1][lr] = v.y;
            At[kk + 2][lr] = v.z; At[kk + 3][lr] = v.w;
        }
#pragma unroll
        for (int kk2 = 0; kk2 < 32; kk2 += 16) {
            int k = kk2 + (t >> 4);
            int c = (t & 15) * 4;
            *(float4*)&Bt[k][c] = *(const float4*)(W + (size_t)(k0 + k) * C + c0 + c);
        }
        __syncthreads();
#pragma unroll
        for (int k = 0; k < 32; k++) {
            float4 a = *(const float4*)&At[k][tr * 4];
            float4 b = *(const float4*)&Bt[k][tc * 4];
            float av[4] = {a.x, a.y, a.z, a.w};
            float bv[4] = {b.x, b.y, b.z, b.w};
#pragma unroll
            for (int i = 0; i < 4; i++)
#pragma unroll
                for (int j = 0; j < 4; j++)
                    acc[i][j] = fmaf(av[i], bv[j], acc[i][j]);
        }
        __syncthreads();
    }
    float4 cv = *(const float4*)(cvec + c0 + tc * 4);
#pragma unroll
    for (int i = 0; i < 4; i++) {
        int r = r0 + tr * 4 + i;
        if (r < NN) {
            float4 o;
            o.x = acc[i][0] + cv.x; o.y = acc[i][1] + cv.y;
            o.z = acc[i][2] + cv.z; o.w = acc[i][3] + cv.w;
            *(float4*)(H + (size_t)r * C + c0 + tc * 4) = o;
        }
    }
}

// ---------------- packed histogram: count (bits 44+) | weight-sum fx2^24 (bits 0..43) ----------------
__global__ void hist_kernel(const int* __restrict__ ei, const float* __restrict__ ew,
                            unsigned long long* __restrict__ hist) {
    int e = blockIdx.x * blockDim.x + threadIdx.x;
    if (e < NE) {
        int c = ei[NE + e];
        unsigned long long pack = (1ULL << 44) | (unsigned long long)(ew[e] * WSCALE);
        atomicAdd(&hist[c], pack);
    }
}

// ---------------- hierarchical exclusive scan: pass 1 (per-block, decode count) ----------------
__global__ __launch_bounds__(256) void scanp1_kernel(const unsigned long long* __restrict__ hist,
                                                     int* __restrict__ rptr,
                                                     int* __restrict__ bsum) {
    __shared__ int s[256];
    const int t = threadIdx.x;
    const int i = blockIdx.x * 256 + t;
    int v = (i < NN) ? (int)(hist[i] >> 44) : 0;
    s[t] = v;
    __syncthreads();
    for (int off = 1; off < 256; off <<= 1) {
        int add = (t >= off) ? s[t - off] : 0;
        __syncthreads();
        s[t] += add;
        __syncthreads();
    }
    if (i < NN) rptr[i] = s[t] - v;           // exclusive within block
    if (t == 255) bsum[blockIdx.x] = s[255];  // block total
}

// ---------------- pass 2: exclusive scan of the 196 block totals ----------------
__global__ __launch_bounds__(256) void scanp2_kernel(const int* __restrict__ bsum,
                                                     int* __restrict__ boff) {
    __shared__ int s[256];
    const int t = threadIdx.x;
    int v = (t < NBLK) ? bsum[t] : 0;
    s[t] = v;
    __syncthreads();
    for (int off = 1; off < 256; off <<= 1) {
        int add = (t >= off) ? s[t - off] : 0;
        __syncthreads();
        s[t] += add;
        __syncthreads();
    }
    if (t < NBLK) boff[t] = s[t] - v;
}

// ---------------- pass 3: add block offsets; init cursor=rptr; decode deg -> dinv ----------------
__global__ void scanp3_kernel(int* __restrict__ rptr, const int* __restrict__ boff,
                              const unsigned long long* __restrict__ hist,
                              int* __restrict__ cursor, float* __restrict__ dinv) {
    int i = blockIdx.x * blockDim.x + threadIdx.x;
    if (i < NN) {
        int rp = rptr[i] + boff[i >> 8];
        rptr[i] = rp;
        cursor[i] = rp;
        float degw = (float)(hist[i] & WMASK) * (1.0f / WSCALE);
        dinv[i] = rsqrtf(degw + 1.0f);   // +1 self-loop; always > 0
    }
    if (i == 0) rptr[NN] = NE;           // total is a constant
}

// ---------------- fill CSR slots with (src, norm): one atomic per edge ----------------
__global__ void fill_kernel(const int* __restrict__ ei, const float* __restrict__ ew,
                            const float* __restrict__ dinv,
                            int* __restrict__ cursor, int* __restrict__ csr_src,
                            float* __restrict__ csr_w) {
    int e = blockIdx.x * blockDim.x + threadIdx.x;
    if (e >= NE) return;
    int r = ei[e], c = ei[NE + e];
    int slot = atomicAdd(&cursor[c], 1);   // cursor pre-initialized to rptr
    csr_src[slot] = r;
    csr_w[slot] = dinv[r] * ew[e] * dinv[c];
}

// ---------------- SpMM + fused BN partial stats ----------------
__global__ __launch_bounds__(256) void spmm_kernel(const int* __restrict__ rptr,
                                                   const int* __restrict__ csr_src,
                                                   const float* __restrict__ csr_w,
                                                   const float* __restrict__ H,
                                                   const float* __restrict__ dinv,
                                                   const float* __restrict__ bg,
                                                   float* __restrict__ OUT,
                                                   float* __restrict__ P) {
    const int nl = threadIdx.x >> 5;                 // node lane 0..7
    const int lane = threadIdx.x & 31;               // channel-group lane
    const int node = blockIdx.x * 8 + nl;            // NN == gridDim*8 exactly
    const int ch = lane * 4;
    int s = rptr[node], e = rptr[node + 1];
    float d = dinv[node];
    float dd = d * d;
    float4 h = *(const float4*)(H + (size_t)node * C + ch);
    float4 acc = make_float4(dd * h.x, dd * h.y, dd * h.z, dd * h.w);
    int j = s;
    for (; j + 2 <= e; j += 2) {
        int r0 = csr_src[j], r1 = csr_src[j + 1];
        float w0 = csr_w[j], w1 = csr_w[j + 1];
        float4 v0 = *(const float4*)(H + (size_t)r0 * C + ch);
        float4 v1 = *(const float4*)(H + (size_t)r1 * C + ch);
        acc.x = fmaf(v0.x, w0, acc.x); acc.y = fmaf(v0.y, w0, acc.y);
        acc.z = fmaf(v0.z, w0, acc.z); acc.w = fmaf(v0.w, w0, acc.w);
        acc.x = fmaf(v1.x, w1, acc.x); acc.y = fmaf(v1.y, w1, acc.y);
        acc.z = fmaf(v1.z, w1, acc.z); acc.w = fmaf(v1.w, w1, acc.w);
    }
    if (j < e) {
        int r0 = csr_src[j];
        float w0 = csr_w[j];
        float4 v0 = *(const float4*)(H + (size_t)r0 * C + ch);
        acc.x = fmaf(v0.x, w0, acc.x); acc.y = fmaf(v0.y, w0, acc.y);
        acc.z = fmaf(v0.z, w0, acc.z); acc.w = fmaf(v0.w, w0, acc.w);
    }
    float4 b = *(const float4*)(bg + ch);
    acc.x += b.x; acc.y += b.y; acc.z += b.z; acc.w += b.w;
    *(float4*)(OUT + (size_t)node * C + ch) = acc;

    // ---- fused BN partials: reduce over the block's 8 nodes, no atomics ----
    __shared__ __align__(16) float4 sred[2][8][32];   // 8 KiB
    float4 sq = make_float4(acc.x * acc.x, acc.y * acc.y, acc.z * acc.z, acc.w * acc.w);
    sred[0][nl][lane] = acc;
    sred[1][nl][lane] = sq;
    __syncthreads();
    if (nl == 0) {
        float4 s0 = sred[0][0][lane], q0 = sred[1][0][lane];
#pragma unroll
        for (int k = 1; k < 8; k++) {
            float4 a = sred[0][k][lane];
            float4 q = sred[1][k][lane];
            s0.x += a.x; s0.y += a.y; s0.z += a.z; s0.w += a.w;
            q0.x += q.x; q0.y += q.y; q0.z += q.z; q0.w += q.w;
        }
        float* row = P + (size_t)blockIdx.x * 256;
        *(float4*)(row + ch) = s0;
        *(float4*)(row + 128 + ch) = q0;
    }
}

// ---------------- reduce spmm-block partials: P[6250][256] -> P2[128][256] ----------------
__global__ __launch_bounds__(256) void reduce1_kernel(const float* __restrict__ P,
                                                      float* __restrict__ P2) {
    const int c = threadIdx.x;
    const int r0 = blockIdx.x * RROWS;
    const int r1 = min(r0 + RROWS, SPB);
    float a0 = 0.f, a1 = 0.f, a2 = 0.f, a3 = 0.f;
    int r = r0;
    for (; r + 4 <= r1; r += 4) {
        a0 += P[(size_t)(r + 0) * 256 + c];
        a1 += P[(size_t)(r + 1) * 256 + c];
        a2 += P[(size_t)(r + 2) * 256 + c];
        a3 += P[(size_t)(r + 3) * 256 + c];
    }
    for (; r < r1; r++) a0 += P[(size_t)r * 256 + c];
    P2[(size_t)blockIdx.x * 256 + c] = (a0 + a1) + (a2 + a3);
}

// ---------------- BN params from P2 ----------------
__global__ void bnparam_kernel(const float* __restrict__ P2,
                               const float* __restrict__ gm, const float* __restrict__ bt,
                               float* __restrict__ sc, float* __restrict__ sh) {
    int c = threadIdx.x;   // 0..127
    float s0 = 0.f, s1 = 0.f, q0 = 0.f, q1 = 0.f;
    for (int k = 0; k < RB; k += 2) {
        s0 += P2[(size_t)k * 256 + c];
        q0 += P2[(size_t)k * 256 + 128 + c];
        s1 += P2[(size_t)(k + 1) * 256 + c];
        q1 += P2[(size_t)(k + 1) * 256 + 128 + c];
    }
    float ssum = s0 + s1, ssq = q0 + q1;
    float mean = ssum / (float)NN;
    float var = ssq / (float)NN - mean * mean;
    var = fmaxf(var, 0.f);
    float r = rsqrtf(var + BN_EPS);
    float s = gm[c] * r;
    sc[c] = s;
    sh[c] = bt[c] - mean * s;
}

// ---------------- final: y = lrelu(BN(h)) @ W_lin + b_lin, in-place ----------------
__global__ __launch_bounds__(256) void final_kernel(float* __restrict__ OUT,
                                                    const float* __restrict__ WL,
                                                    const float* __restrict__ bl,
                                                    const float* __restrict__ sc,
                                                    const float* __restrict__ sh) {
    __shared__ __align__(16) float At[32][68];    // lrelu(BN(h))^T chunk
    __shared__ __align__(16) float Bt[32][132];   // W_lin chunk (all 128 cols)
    const int t = threadIdx.x;
    const int r0 = blockIdx.x * 64;
    const int tr = t >> 4, tc = t & 15;
    float acc[4][8] = {};
    for (int k0 = 0; k0 < 128; k0 += 32) {
#pragma unroll
        for (int rr = 0; rr < 64; rr += 32) {
            int lr = rr + (t >> 3);
            int r = r0 + lr;
            int kk = (t & 7) * 4;
            float4 v = make_float4(0.f, 0.f, 0.f, 0.f);
            if (r < NN) v = *(const float4*)(OUT + (size_t)r * C + k0 + kk);
            float4 s4 = *(const float4*)(sc + k0 + kk);
            float4 h4 = *(const float4*)(sh + k0 + kk);
            float a0 = fmaf(v.x, s4.x, h4.x); a0 = a0 >= 0.f ? a0 : NEG * a0;
            float a1 = fmaf(v.y, s4.y, h4.y); a1 = a1 >= 0.f ? a1 : NEG * a1;
            float a2 = fmaf(v.z, s4.z, h4.z); a2 = a2 >= 0.f ? a2 : NEG * a2;
            float a3 = fmaf(v.w, s4.w, h4.w); a3 = a3 >= 0.f ? a3 : NEG * a3;
            At[kk + 0][lr] = a0; At[kk + 1][lr] = a1;
            At[kk + 2][lr] = a2; At[kk + 3][lr] = a3;
        }
#pragma unroll
        for (int kk2 = 0; kk2 < 32; kk2 += 8) {
            int k = kk2 + (t >> 5);
            int c = (t & 31) * 4;
            *(float4*)&Bt[k][c] = *(const float4*)(WL + (size_t)(k0 + k) * C + c);
        }
        __syncthreads();
#pragma unroll
        for (int k = 0; k < 32; k++) {
            float4 a = *(const float4*)&At[k][tr * 4];
            float4 b0 = *(const float4*)&Bt[k][tc * 8];
            float4 b1 = *(const float4*)&Bt[k][tc * 8 + 4];
            float av[4] = {a.x, a.y, a.z, a.w};
            float bv[8] = {b0.x, b0.y, b0.z, b0.w, b1.x, b1.y, b1.z, b1.w};
#pragma unroll
            for (int i = 0; i < 4; i++)
#pragma unroll
                for (int j = 0; j < 8; j++)
                    acc[i][j] = fmaf(av[i], bv[j], acc[i][j]);
        }
        __syncthreads();
    }
    float4 bl0 = *(const float4*)(bl + tc * 8);
    float4 bl1 = *(const float4*)(bl + tc * 8 + 4);
#pragma unroll
    for (int i = 0; i < 4; i++) {
        int r = r0 + tr * 4 + i;
        if (r < NN) {
            float4 o0, o1;
            o0.x = acc[i][0] + bl0.x; o0.y = acc[i][1] + bl0.y;
            o0.z = acc[i][2] + bl0.z; o0.w = acc[i][3] + bl0.w;
            o1.x = acc[i][4] + bl1.x; o1.y = acc[i][5] + bl1.y;
            o1.z = acc[i][6] + bl1.z; o1.w = acc[i][7] + bl1.w;
            *(float4*)(OUT + (size_t)r * C + tc * 8) = o0;
            *(float4*)(OUT + (size_t)r * C + tc * 8 + 4) = o1;
        }
    }
}

extern "C" void kernel_launch(void* const* d_in, const int* in_sizes, int n_in,
                              void* d_out, int out_size, void* d_ws, size_t ws_size,
                              hipStream_t stream) {
    const float* x  = (const float*)d_in[0];
    const int*   ei = (const int*)d_in[1];
    const float* ew = (const float*)d_in[2];
    const float* td = (const float*)d_in[3];
    const float* mf = (const float*)d_in[4];
    const float* Wg = (const float*)d_in[5];
    const float* bg = (const float*)d_in[6];
    const float* gm = (const float*)d_in[7];
    const float* bt = (const float*)d_in[8];
    const float* Wl = (const float*)d_in[9];
    const float* bl = (const float*)d_in[10];
    float* out = (float*)d_out;

    // workspace layout
    float* h1     = (float*)d_ws;                        // NN*C floats (25.6 MB, 8B-aligned end)
    unsigned long long* hist = (unsigned long long*)(h1 + (size_t)NN * C);  // NN u64 [zeroed]
    int*   cursor = (int*)(hist + NN);                   // NN (init in scanp3)
    float* dinv   = (float*)(cursor + NN);               // NN
    float* cvec   = dinv + NN;                           // C
    float* sc     = cvec + C;                            // C
    float* sh     = sc + C;                              // C
    int*   rptr   = (int*)(sh + C);                      // NN+1 (+pad)
    int*   bsum   = rptr + NN + 8;                       // NBLK
    int*   boff   = bsum + NBLK;                         // NBLK
    int*   csr_src= boff + NBLK + 8;                     // NE
    float* csr_w  = (float*)(csr_src + NE);              // NE
    float* P      = csr_w + NE;                          // SPB*256 (6.4 MB)
    float* P2     = P + (size_t)SPB * 256;               // RB*256

    zero_kernel<<<128, 256, 0, stream>>>((float*)hist, 2L * NN);
    cvec_kernel<<<1, 128, 0, stream>>>(td, mf, Wg, cvec);
    gemm1_kernel<<<dim3((NN + 63) / 64, 2), 256, 0, stream>>>(x, Wg, cvec, h1);
    hist_kernel<<<(NE + 255) / 256, 256, 0, stream>>>(ei, ew, hist);
    scanp1_kernel<<<NBLK, 256, 0, stream>>>(hist, rptr, bsum);
    scanp2_kernel<<<1, 256, 0, stream>>>(bsum, boff);
    scanp3_kernel<<<NBLK, 256, 0, stream>>>(rptr, boff, hist, cursor, dinv);
    fill_kernel<<<(NE + 255) / 256, 256, 0, stream>>>(ei, ew, dinv, cursor, csr_src, csr_w);
    spmm_kernel<<<SPB, 256, 0, stream>>>(rptr, csr_src, csr_w, h1, dinv, bg, out, P);
    reduce1_kernel<<<RB, 256, 0, stream>>>(P, P2);
    bnparam_kernel<<<1, 128, 0, stream>>>(P2, gm, bt, sc, sh);
    final_kernel<<<(NN + 63) / 64, 256, 0, stream>>>(out, Wl, bl, sc, sh);
}

// Round 6
// 173.494 us; speedup vs baseline: 5.8704x; 1.0658x over previous
//
#include <hip/hip_runtime.h>
#include <hip/hip_bf16.h>

#define NN 50000
#define NE 500000
#define C 128
#define NBLK ((NN + 255) / 256)       // 196 scan blocks
#define SPB (NN / 8)                  // 6250 spmm blocks (exact: 50000 = 6250*8)
#define RB 128                        // reduce1 blocks
#define RROWS ((SPB + RB - 1) / RB)   // 49 rows per reduce1 block
#define BN_EPS 1e-5f
#define NEG 0.01f
#define WSCALE 16777216.0f            // 2^24 fixed-point for packed degree
#define WMASK  0xFFFFFFFFFFFULL      // low 44 bits

// bf16 helpers
__device__ inline unsigned short f2bf(float f) {            // round-to-nearest-even
    unsigned int u = __float_as_uint(f);
    unsigned int r = (u + 0x7fffu + ((u >> 16) & 1u)) >> 16;
    return (unsigned short)r;
}
__device__ inline float4 bf4_to_f4(uint2 u) {               // 4 packed bf16 -> 4 f32
    float4 r;
    r.x = __uint_as_float(u.x << 16);
    r.y = __uint_as_float(u.x & 0xffff0000u);
    r.z = __uint_as_float(u.y << 16);
    r.w = __uint_as_float(u.y & 0xffff0000u);
    return r;
}

// ---------------- zero ----------------
__global__ void zero_kernel(float* __restrict__ p, long n) {
    long i = (long)blockIdx.x * blockDim.x + threadIdx.x;
    long s = (long)gridDim.x * blockDim.x;
    for (; i < n; i += s) p[i] = 0.f;
}

// ---------------- cvec: enc @ W_gcn[128:144,:] ----------------
__global__ void cvec_kernel(const float* __restrict__ td, const float* __restrict__ mf,
                            const float* __restrict__ Wg, float* __restrict__ cvec) {
    int o = threadIdx.x;
    float t = td[0];
    float acc = 0.f;
#pragma unroll
    for (int j = 0; j < 16; j++) {
        float s = sinf(t * mf[j] * 3.14159265358979323846f);
        acc = fmaf(s, Wg[(128 + j) * C + o], acc);
    }
    cvec[o] = acc;
}

// ---------------- GEMM1: h1b = bf16(x @ Wg[0:128,:] + cvec) ----------------
__global__ __launch_bounds__(256) void gemm1_kernel(const float* __restrict__ X,
                                                    const float* __restrict__ W,
                                                    const float* __restrict__ cvec,
                                                    unsigned short* __restrict__ Hb) {
    __shared__ __align__(16) float At[32][68];   // x^T chunk: At[k][r]
    __shared__ __align__(16) float Bt[32][68];   // W chunk:  Bt[k][c]
    const int t = threadIdx.x;
    const int r0 = blockIdx.x * 64;
    const int c0 = blockIdx.y * 64;
    const int tr = t >> 4, tc = t & 15;
    float acc[4][4] = {};
    for (int k0 = 0; k0 < 128; k0 += 32) {
#pragma unroll
        for (int rr = 0; rr < 64; rr += 32) {
            int lr = rr + (t >> 3);
            int r = r0 + lr;
            int kk = (t & 7) * 4;
            float4 v = make_float4(0.f, 0.f, 0.f, 0.f);
            if (r < NN) v = *(const float4*)(X + (size_t)r * C + k0 + kk);
            At[kk + 0][lr] = v.x; At[kk + 1][lr] = v.y;
            At[kk + 2][lr] = v.z; At[kk + 3][lr] = v.w;
        }
#pragma unroll
        for (int kk2 = 0; kk2 < 32; kk2 += 16) {
            int k = kk2 + (t >> 4);
            int c = (t & 15) * 4;
            *(float4*)&Bt[k][c] = *(const float4*)(W + (size_t)(k0 + k) * C + c0 + c);
        }
        __syncthreads();
#pragma unroll
        for (int k = 0; k < 32; k++) {
            float4 a = *(const float4*)&At[k][tr * 4];
            float4 b = *(const float4*)&Bt[k][tc * 4];
            float av[4] = {a.x, a.y, a.z, a.w};
            float bv[4] = {b.x, b.y, b.z, b.w};
#pragma unroll
            for (int i = 0; i < 4; i++)
#pragma unroll
                for (int j = 0; j < 4; j++)
                    acc[i][j] = fmaf(av[i], bv[j], acc[i][j]);
        }
        __syncthreads();
    }
    float4 cv = *(const float4*)(cvec + c0 + tc * 4);
#pragma unroll
    for (int i = 0; i < 4; i++) {
        int r = r0 + tr * 4 + i;
        if (r < NN) {
            uint2 o;
            o.x = (unsigned int)f2bf(acc[i][0] + cv.x) | ((unsigned int)f2bf(acc[i][1] + cv.y) << 16);
            o.y = (unsigned int)f2bf(acc[i][2] + cv.z) | ((unsigned int)f2bf(acc[i][3] + cv.w) << 16);
            *(uint2*)(Hb + (size_t)r * C + c0 + tc * 4) = o;
        }
    }
}

// ---------------- packed histogram: count (bits 44+) | weight-sum fx2^24 (bits 0..43) ----------------
__global__ void hist_kernel(const int* __restrict__ ei, const float* __restrict__ ew,
                            unsigned long long* __restrict__ hist) {
    int e = blockIdx.x * blockDim.x + threadIdx.x;
    if (e < NE) {
        int c = ei[NE + e];
        unsigned long long pack = (1ULL << 44) | (unsigned long long)(ew[e] * WSCALE);
        atomicAdd(&hist[c], pack);
    }
}

// ---------------- hierarchical exclusive scan: pass 1 (per-block, decode count) ----------------
__global__ __launch_bounds__(256) void scanp1_kernel(const unsigned long long* __restrict__ hist,
                                                     int* __restrict__ rptr,
                                                     int* __restrict__ bsum) {
    __shared__ int s[256];
    const int t = threadIdx.x;
    const int i = blockIdx.x * 256 + t;
    int v = (i < NN) ? (int)(hist[i] >> 44) : 0;
    s[t] = v;
    __syncthreads();
    for (int off = 1; off < 256; off <<= 1) {
        int add = (t >= off) ? s[t - off] : 0;
        __syncthreads();
        s[t] += add;
        __syncthreads();
    }
    if (i < NN) rptr[i] = s[t] - v;           // exclusive within block
    if (t == 255) bsum[blockIdx.x] = s[255];  // block total
}

// ---------------- pass 2: exclusive scan of the 196 block totals ----------------
__global__ __launch_bounds__(256) void scanp2_kernel(const int* __restrict__ bsum,
                                                     int* __restrict__ boff) {
    __shared__ int s[256];
    const int t = threadIdx.x;
    int v = (t < NBLK) ? bsum[t] : 0;
    s[t] = v;
    __syncthreads();
    for (int off = 1; off < 256; off <<= 1) {
        int add = (t >= off) ? s[t - off] : 0;
        __syncthreads();
        s[t] += add;
        __syncthreads();
    }
    if (t < NBLK) boff[t] = s[t] - v;
}

// ---------------- pass 3: add block offsets; init cursor=rptr; decode deg -> dinv ----------------
__global__ void scanp3_kernel(int* __restrict__ rptr, const int* __restrict__ boff,
                              const unsigned long long* __restrict__ hist,
                              int* __restrict__ cursor, float* __restrict__ dinv) {
    int i = blockIdx.x * blockDim.x + threadIdx.x;
    if (i < NN) {
        int rp = rptr[i] + boff[i >> 8];
        rptr[i] = rp;
        cursor[i] = rp;
        float degw = (float)(hist[i] & WMASK) * (1.0f / WSCALE);
        dinv[i] = rsqrtf(degw + 1.0f);   // +1 self-loop; always > 0
    }
    if (i == 0) rptr[NN] = NE;           // total is a constant
}

// ---------------- fill CSR slots with interleaved (src, norm): one atomic + one 8B store ----------------
__global__ void fill_kernel(const int* __restrict__ ei, const float* __restrict__ ew,
                            const float* __restrict__ dinv,
                            int* __restrict__ cursor, int2* __restrict__ csr) {
    int e = blockIdx.x * blockDim.x + threadIdx.x;
    if (e >= NE) return;
    int r = ei[e], c = ei[NE + e];
    int slot = atomicAdd(&cursor[c], 1);   // cursor pre-initialized to rptr
    float w = dinv[r] * ew[e] * dinv[c];
    csr[slot] = make_int2(r, __float_as_int(w));
}

// ---------------- SpMM (bf16 gather, f32 accum) + fused BN partial stats ----------------
__global__ __launch_bounds__(256) void spmm_kernel(const int* __restrict__ rptr,
                                                   const int2* __restrict__ csr,
                                                   const unsigned short* __restrict__ Hb,
                                                   const float* __restrict__ dinv,
                                                   const float* __restrict__ bg,
                                                   float* __restrict__ OUT,
                                                   float* __restrict__ P) {
    const int nl = threadIdx.x >> 5;                 // node lane 0..7
    const int lane = threadIdx.x & 31;               // channel-group lane
    const int node = blockIdx.x * 8 + nl;            // NN == gridDim*8 exactly
    const int ch = lane * 4;
    int s = rptr[node], e = rptr[node + 1];
    float d = dinv[node];
    float dd = d * d;
    float4 h = bf4_to_f4(*(const uint2*)(Hb + (size_t)node * C + ch));
    float4 acc = make_float4(dd * h.x, dd * h.y, dd * h.z, dd * h.w);
    int j = s;
    for (; j + 2 <= e; j += 2) {
        int2 e0 = csr[j], e1 = csr[j + 1];
        float w0 = __int_as_float(e0.y), w1 = __int_as_float(e1.y);
        float4 v0 = bf4_to_f4(*(const uint2*)(Hb + (size_t)e0.x * C + ch));
        float4 v1 = bf4_to_f4(*(const uint2*)(Hb + (size_t)e1.x * C + ch));
        acc.x = fmaf(v0.x, w0, acc.x); acc.y = fmaf(v0.y, w0, acc.y);
        acc.z = fmaf(v0.z, w0, acc.z); acc.w = fmaf(v0.w, w0, acc.w);
        acc.x = fmaf(v1.x, w1, acc.x); acc.y = fmaf(v1.y, w1, acc.y);
        acc.z = fmaf(v1.z, w1, acc.z); acc.w = fmaf(v1.w, w1, acc.w);
    }
    if (j < e) {
        int2 e0 = csr[j];
        float w0 = __int_as_float(e0.y);
        float4 v0 = bf4_to_f4(*(const uint2*)(Hb + (size_t)e0.x * C + ch));
        acc.x = fmaf(v0.x, w0, acc.x); acc.y = fmaf(v0.y, w0, acc.y);
        acc.z = fmaf(v0.z, w0, acc.z); acc.w = fmaf(v0.w, w0, acc.w);
    }
    float4 b = *(const float4*)(bg + ch);
    acc.x += b.x; acc.y += b.y; acc.z += b.z; acc.w += b.w;
    *(float4*)(OUT + (size_t)node * C + ch) = acc;

    // ---- fused BN partials: reduce over the block's 8 nodes, no atomics ----
    __shared__ __align__(16) float4 sred[2][8][32];   // 8 KiB
    float4 sq = make_float4(acc.x * acc.x, acc.y * acc.y, acc.z * acc.z, acc.w * acc.w);
    sred[0][nl][lane] = acc;
    sred[1][nl][lane] = sq;
    __syncthreads();
    if (nl == 0) {
        float4 s0 = sred[0][0][lane], q0 = sred[1][0][lane];
#pragma unroll
        for (int k = 1; k < 8; k++) {
            float4 a = sred[0][k][lane];
            float4 q = sred[1][k][lane];
            s0.x += a.x; s0.y += a.y; s0.z += a.z; s0.w += a.w;
            q0.x += q.x; q0.y += q.y; q0.z += q.z; q0.w += q.w;
        }
        float* row = P + (size_t)blockIdx.x * 256;
        *(float4*)(row + ch) = s0;
        *(float4*)(row + 128 + ch) = q0;
    }
}

// ---------------- reduce spmm-block partials: P[6250][256] -> P2[128][256] ----------------
__global__ __launch_bounds__(256) void reduce1_kernel(const float* __restrict__ P,
                                                      float* __restrict__ P2) {
    const int c = threadIdx.x;
    const int r0 = blockIdx.x * RROWS;
    const int r1 = min(r0 + RROWS, SPB);
    float a0 = 0.f, a1 = 0.f, a2 = 0.f, a3 = 0.f;
    int r = r0;
    for (; r + 4 <= r1; r += 4) {
        a0 += P[(size_t)(r + 0) * 256 + c];
        a1 += P[(size_t)(r + 1) * 256 + c];
        a2 += P[(size_t)(r + 2) * 256 + c];
        a3 += P[(size_t)(r + 3) * 256 + c];
    }
    for (; r < r1; r++) a0 += P[(size_t)r * 256 + c];
    P2[(size_t)blockIdx.x * 256 + c] = (a0 + a1) + (a2 + a3);
}

// ---------------- BN params from P2 ----------------
__global__ void bnparam_kernel(const float* __restrict__ P2,
                               const float* __restrict__ gm, const float* __restrict__ bt,
                               float* __restrict__ sc, float* __restrict__ sh) {
    int c = threadIdx.x;   // 0..127
    float s0 = 0.f, s1 = 0.f, q0 = 0.f, q1 = 0.f;
    for (int k = 0; k < RB; k += 2) {
        s0 += P2[(size_t)k * 256 + c];
        q0 += P2[(size_t)k * 256 + 128 + c];
        s1 += P2[(size_t)(k + 1) * 256 + c];
        q1 += P2[(size_t)(k + 1) * 256 + 128 + c];
    }
    float ssum = s0 + s1, ssq = q0 + q1;
    float mean = ssum / (float)NN;
    float var = ssq / (float)NN - mean * mean;
    var = fmaxf(var, 0.f);
    float r = rsqrtf(var + BN_EPS);
    float s = gm[c] * r;
    sc[c] = s;
    sh[c] = bt[c] - mean * s;
}

// ---------------- final: y = lrelu(BN(h)) @ W_lin + b_lin, in-place ----------------
__global__ __launch_bounds__(256) void final_kernel(float* __restrict__ OUT,
                                                    const float* __restrict__ WL,
                                                    const float* __restrict__ bl,
                                                    const float* __restrict__ sc,
                                                    const float* __restrict__ sh) {
    __shared__ __align__(16) float At[32][68];    // lrelu(BN(h))^T chunk
    __shared__ __align__(16) float Bt[32][132];   // W_lin chunk (all 128 cols)
    const int t = threadIdx.x;
    const int r0 = blockIdx.x * 64;
    const int tr = t >> 4, tc = t & 15;
    float acc[4][8] = {};
    for (int k0 = 0; k0 < 128; k0 += 32) {
#pragma unroll
        for (int rr = 0; rr < 64; rr += 32) {
            int lr = rr + (t >> 3);
            int r = r0 + lr;
            int kk = (t & 7) * 4;
            float4 v = make_float4(0.f, 0.f, 0.f, 0.f);
            if (r < NN) v = *(const float4*)(OUT + (size_t)r * C + k0 + kk);
            float4 s4 = *(const float4*)(sc + k0 + kk);
            float4 h4 = *(const float4*)(sh + k0 + kk);
            float a0 = fmaf(v.x, s4.x, h4.x); a0 = a0 >= 0.f ? a0 : NEG * a0;
            float a1 = fmaf(v.y, s4.y, h4.y); a1 = a1 >= 0.f ? a1 : NEG * a1;
            float a2 = fmaf(v.z, s4.z, h4.z); a2 = a2 >= 0.f ? a2 : NEG * a2;
            float a3 = fmaf(v.w, s4.w, h4.w); a3 = a3 >= 0.f ? a3 : NEG * a3;
            At[kk + 0][lr] = a0; At[kk + 1][lr] = a1;
            At[kk + 2][lr] = a2; At[kk + 3][lr] = a3;
        }
#pragma unroll
        for (int kk2 = 0; kk2 < 32; kk2 += 8) {
            int k = kk2 + (t >> 5);
            int c = (t & 31) * 4;
            *(float4*)&Bt[k][c] = *(const float4*)(WL + (size_t)(k0 + k) * C + c);
        }
        __syncthreads();
#pragma unroll
        for (int k = 0; k < 32; k++) {
            float4 a = *(const float4*)&At[k][tr * 4];
            float4 b0 = *(const float4*)&Bt[k][tc * 8];
            float4 b1 = *(const float4*)&Bt[k][tc * 8 + 4];
            float av[4] = {a.x, a.y, a.z, a.w};
            float bv[8] = {b0.x, b0.y, b0.z, b0.w, b1.x, b1.y, b1.z, b1.w};
#pragma unroll
            for (int i = 0; i < 4; i++)
#pragma unroll
                for (int j = 0; j < 8; j++)
                    acc[i][j] = fmaf(av[i], bv[j], acc[i][j]);
        }
        __syncthreads();
    }
    float4 bl0 = *(const float4*)(bl + tc * 8);
    float4 bl1 = *(const float4*)(bl + tc * 8 + 4);
#pragma unroll
    for (int i = 0; i < 4; i++) {
        int r = r0 + tr * 4 + i;
        if (r < NN) {
            float4 o0, o1;
            o0.x = acc[i][0] + bl0.x; o0.y = acc[i][1] + bl0.y;
            o0.z = acc[i][2] + bl0.z; o0.w = acc[i][3] + bl0.w;
            o1.x = acc[i][4] + bl1.x; o1.y = acc[i][5] + bl1.y;
            o1.z = acc[i][6] + bl1.z; o1.w = acc[i][7] + bl1.w;
            *(float4*)(OUT + (size_t)r * C + tc * 8) = o0;
            *(float4*)(OUT + (size_t)r * C + tc * 8 + 4) = o1;
        }
    }
}

extern "C" void kernel_launch(void* const* d_in, const int* in_sizes, int n_in,
                              void* d_out, int out_size, void* d_ws, size_t ws_size,
                              hipStream_t stream) {
    const float* x  = (const float*)d_in[0];
    const int*   ei = (const int*)d_in[1];
    const float* ew = (const float*)d_in[2];
    const float* td = (const float*)d_in[3];
    const float* mf = (const float*)d_in[4];
    const float* Wg = (const float*)d_in[5];
    const float* bg = (const float*)d_in[6];
    const float* gm = (const float*)d_in[7];
    const float* bt = (const float*)d_in[8];
    const float* Wl = (const float*)d_in[9];
    const float* bl = (const float*)d_in[10];
    float* out = (float*)d_out;

    // workspace layout
    unsigned short* h1b = (unsigned short*)d_ws;         // NN*C bf16 (12.8 MB)
    unsigned long long* hist = (unsigned long long*)(h1b + (size_t)NN * C);  // NN u64 [zeroed]
    int*   cursor = (int*)(hist + NN);                   // NN (init in scanp3)
    float* dinv   = (float*)(cursor + NN);               // NN
    float* cvec   = dinv + NN;                           // C
    float* sc     = cvec + C;                            // C
    float* sh     = sc + C;                              // C
    int*   rptr   = (int*)(sh + C);                      // NN+1 (+pad)
    int*   bsum   = rptr + NN + 8;                       // NBLK
    int*   boff   = bsum + NBLK;                         // NBLK
    int2*  csr    = (int2*)(boff + NBLK + 9);            // NE int2 (8B-aligned: offset parity kept even)
    float* P      = (float*)(csr + NE);                  // SPB*256 (6.4 MB)
    float* P2     = P + (size_t)SPB * 256;               // RB*256

    zero_kernel<<<128, 256, 0, stream>>>((float*)hist, 2L * NN);
    cvec_kernel<<<1, 128, 0, stream>>>(td, mf, Wg, cvec);
    gemm1_kernel<<<dim3((NN + 63) / 64, 2), 256, 0, stream>>>(x, Wg, cvec, h1b);
    hist_kernel<<<(NE + 255) / 256, 256, 0, stream>>>(ei, ew, hist);
    scanp1_kernel<<<NBLK, 256, 0, stream>>>(hist, rptr, bsum);
    scanp2_kernel<<<1, 256, 0, stream>>>(bsum, boff);
    scanp3_kernel<<<NBLK, 256, 0, stream>>>(rptr, boff, hist, cursor, dinv);
    fill_kernel<<<(NE + 255) / 256, 256, 0, stream>>>(ei, ew, dinv, cursor, csr);
    spmm_kernel<<<SPB, 256, 0, stream>>>(rptr, csr, h1b, dinv, bg, out, P);
    reduce1_kernel<<<RB, 256, 0, stream>>>(P, P2);
    bnparam_kernel<<<1, 128, 0, stream>>>(P2, gm, bt, sc, sh);
    final_kernel<<<(NN + 63) / 64, 256, 0, stream>>>(out, Wl, bl, sc, sh);
}

// Round 7
// 147.861 us; speedup vs baseline: 6.8881x; 1.1734x over previous
//
#include <hip/hip_runtime.h>
#include <hip/hip_bf16.h>

#define NN 50000
#define NE 500000
#define C 128
#define NBLK ((NN + 255) / 256)       // 196 scan blocks
#define SPB (NN / 8)                  // 6250 spmm blocks (exact: 50000 = 6250*8)
#define RB 128                        // reduce1 blocks
#define RROWS ((SPB + RB - 1) / RB)   // 49 rows per reduce1 block
#define GB ((NN + 63) / 64)           // 782 gemm blocks
#define BN_EPS 1e-5f
#define NEG 0.01f
#define WSCALE 16777216.0f            // 2^24 fixed-point for packed degree
#define WMASK  0xFFFFFFFFFFFULL      // low 44 bits

typedef __attribute__((ext_vector_type(8))) short bf16x8;
typedef __attribute__((ext_vector_type(4))) float f32x4;

// bf16 helpers
__device__ inline unsigned short f2bf(float f) {            // round-to-nearest-even
    unsigned int u = __float_as_uint(f);
    unsigned int r = (u + 0x7fffu + ((u >> 16) & 1u)) >> 16;
    return (unsigned short)r;
}
__device__ inline unsigned int pack2(float a, float b) {
    return (unsigned int)f2bf(a) | ((unsigned int)f2bf(b) << 16);
}
__device__ inline float4 bf4_to_f4(uint2 u) {               // 4 packed bf16 -> 4 f32
    float4 r;
    r.x = __uint_as_float(u.x << 16);
    r.y = __uint_as_float(u.x & 0xffff0000u);
    r.z = __uint_as_float(u.y << 16);
    r.w = __uint_as_float(u.y & 0xffff0000u);
    return r;
}

// ---------------- zero ----------------
__global__ void zero_kernel(float* __restrict__ p, long n) {
    long i = (long)blockIdx.x * blockDim.x + threadIdx.x;
    long s = (long)gridDim.x * blockDim.x;
    for (; i < n; i += s) p[i] = 0.f;
}

// ---------------- wprep: W[k][c] f32 -> Wt[c][k] bf16, 16B-granule XOR-swizzled ----------------
// u32 slot(c, ku) = c*64 + (((ku>>2) ^ (c&15))<<2 | (ku&3)),  ku = k/2 (packed pairs)
__global__ __launch_bounds__(256) void wprep_kernel(const float* __restrict__ Wg,
                                                    const float* __restrict__ Wl,
                                                    unsigned int* __restrict__ Wgt,
                                                    unsigned int* __restrict__ Wlt) {
    const int t = threadIdx.x;
    const int col = t >> 1;
    const int half = t & 1;
    for (int j = 0; j < 32; j++) {
        int ku = half * 32 + j;
        int k0 = 2 * ku;
        unsigned int g = (unsigned int)((ku >> 2) ^ (col & 15));
        unsigned int slot = (unsigned int)col * 64u + (g << 2) + (unsigned int)(ku & 3);
        Wgt[slot] = pack2(Wg[(size_t)k0 * C + col], Wg[(size_t)(k0 + 1) * C + col]);
        Wlt[slot] = pack2(Wl[(size_t)k0 * C + col], Wl[(size_t)(k0 + 1) * C + col]);
    }
}

// ---------------- cvec: enc @ W_gcn[128:144,:] ----------------
__global__ void cvec_kernel(const float* __restrict__ td, const float* __restrict__ mf,
                            const float* __restrict__ Wg, float* __restrict__ cvec) {
    int o = threadIdx.x;
    float t = td[0];
    float acc = 0.f;
#pragma unroll
    for (int j = 0; j < 16; j++) {
        float s = sinf(t * mf[j] * 3.14159265358979323846f);
        acc = fmaf(s, Wg[(128 + j) * C + o], acc);
    }
    cvec[o] = acc;
}

// ---------------- GEMM1 (MFMA): h1b = bf16(x @ Wg[0:128,:] + cvec) ----------------
// 4 waves/block, 64 rows x 128 cols per block. A from global (f32->bf16), B from LDS.
__global__ __launch_bounds__(256) void gemm1_kernel(const float* __restrict__ X,
                                                    const unsigned int* __restrict__ Wt,
                                                    const float* __restrict__ cvec,
                                                    unsigned short* __restrict__ Hb) {
    __shared__ unsigned int wsh[8192];   // 32 KB, swizzled [col][ku]
    const int t = threadIdx.x;
#pragma unroll
    for (int i = 0; i < 8; i++)
        ((uint4*)wsh)[t + i * 256] = ((const uint4*)Wt)[t + i * 256];

    const int lane = t & 63;
    const int wid = t >> 6;
    const int lrow = lane & 15;
    const int kb = lane >> 4;            // 0..3
    const int row = blockIdx.x * 64 + wid * 16 + lrow;
    const float* xrow = X + (size_t)min(row, NN - 1) * C;

    f32x4 acc[8];
#pragma unroll
    for (int n = 0; n < 8; n++) acc[n] = (f32x4){0.f, 0.f, 0.f, 0.f};
    __syncthreads();

#pragma unroll
    for (int ks = 0; ks < 4; ks++) {
        float4 a0 = *(const float4*)(xrow + ks * 32 + kb * 8);
        float4 a1 = *(const float4*)(xrow + ks * 32 + kb * 8 + 4);
        union { unsigned int u[4]; bf16x8 v; } af;
        af.u[0] = pack2(a0.x, a0.y); af.u[1] = pack2(a0.z, a0.w);
        af.u[2] = pack2(a1.x, a1.y); af.u[3] = pack2(a1.z, a1.w);
        const unsigned int gp = (unsigned int)((ks * 4 + kb) ^ lrow);
#pragma unroll
        for (int n = 0; n < 8; n++) {
            int col = n * 16 + lrow;
            union { uint4 q; bf16x8 v; } bfm;
            bfm.q = *(const uint4*)&wsh[col * 64 + gp * 4];
            acc[n] = __builtin_amdgcn_mfma_f32_16x16x32_bf16(af.v, bfm.v, acc[n], 0, 0, 0);
        }
    }
    const int orow = blockIdx.x * 64 + wid * 16 + kb * 4;   // C/D: col=lane&15, row=(lane>>4)*4+i
#pragma unroll
    for (int n = 0; n < 8; n++) {
        int col = n * 16 + lrow;
        float cv = cvec[col];
#pragma unroll
        for (int i = 0; i < 4; i++) {
            int r = orow + i;
            if (r < NN) Hb[(size_t)r * C + col] = f2bf(acc[n][i] + cv);
        }
    }
}

// ---------------- packed histogram + per-edge rank (atomicAdd return) ----------------
__global__ void hist_kernel(const int* __restrict__ ei, const float* __restrict__ ew,
                            unsigned long long* __restrict__ hist, int* __restrict__ rank) {
    int e = blockIdx.x * blockDim.x + threadIdx.x;
    if (e < NE) {
        int c = ei[NE + e];
        unsigned long long pack = (1ULL << 44) | (unsigned long long)(ew[e] * WSCALE);
        unsigned long long old = atomicAdd(&hist[c], pack);
        rank[e] = (int)(old >> 44);
    }
}

// ---------------- hierarchical exclusive scan: pass 1 (per-block, decode count) ----------------
__global__ __launch_bounds__(256) void scanp1_kernel(const unsigned long long* __restrict__ hist,
                                                     int* __restrict__ rptr,
                                                     int* __restrict__ bsum) {
    __shared__ int s[256];
    const int t = threadIdx.x;
    const int i = blockIdx.x * 256 + t;
    int v = (i < NN) ? (int)(hist[i] >> 44) : 0;
    s[t] = v;
    __syncthreads();
    for (int off = 1; off < 256; off <<= 1) {
        int add = (t >= off) ? s[t - off] : 0;
        __syncthreads();
        s[t] += add;
        __syncthreads();
    }
    if (i < NN) rptr[i] = s[t] - v;           // exclusive within block
    if (t == 255) bsum[blockIdx.x] = s[255];  // block total
}

// ---------------- pass 2: exclusive scan of the 196 block totals ----------------
__global__ __launch_bounds__(256) void scanp2_kernel(const int* __restrict__ bsum,
                                                     int* __restrict__ boff) {
    __shared__ int s[256];
    const int t = threadIdx.x;
    int v = (t < NBLK) ? bsum[t] : 0;
    s[t] = v;
    __syncthreads();
    for (int off = 1; off < 256; off <<= 1) {
        int add = (t >= off) ? s[t - off] : 0;
        __syncthreads();
        s[t] += add;
        __syncthreads();
    }
    if (t < NBLK) boff[t] = s[t] - v;
}

// ---------------- pass 3: add block offsets; decode deg -> dinv ----------------
__global__ void scanp3_kernel(int* __restrict__ rptr, const int* __restrict__ boff,
                              const unsigned long long* __restrict__ hist,
                              float* __restrict__ dinv) {
    int i = blockIdx.x * blockDim.x + threadIdx.x;
    if (i < NN) {
        rptr[i] += boff[i >> 8];
        float degw = (float)(hist[i] & WMASK) * (1.0f / WSCALE);
        dinv[i] = rsqrtf(degw + 1.0f);   // +1 self-loop; always > 0
    }
    if (i == 0) rptr[NN] = NE;           // total is a constant
}

// ---------------- fill CSR: no atomic — slot = rptr[c] + rank[e] ----------------
__global__ void fill_kernel(const int* __restrict__ ei, const float* __restrict__ ew,
                            const float* __restrict__ dinv, const int* __restrict__ rptr,
                            const int* __restrict__ rank, int2* __restrict__ csr) {
    int e = blockIdx.x * blockDim.x + threadIdx.x;
    if (e >= NE) return;
    int r = ei[e], c = ei[NE + e];
    int slot = rptr[c] + rank[e];
    float w = dinv[r] * ew[e] * dinv[c];
    csr[slot] = make_int2(r, __float_as_int(w));
}

// ---------------- SpMM (bf16 gather, f32 accum) + fused BN partial stats ----------------
__global__ __launch_bounds__(256) void spmm_kernel(const int* __restrict__ rptr,
                                                   const int2* __restrict__ csr,
                                                   const unsigned short* __restrict__ Hb,
                                                   const float* __restrict__ dinv,
                                                   const float* __restrict__ bg,
                                                   float* __restrict__ OUT,
                                                   float* __restrict__ P) {
    const int nl = threadIdx.x >> 5;                 // node lane 0..7
    const int lane = threadIdx.x & 31;               // channel-group lane
    const int node = blockIdx.x * 8 + nl;            // NN == gridDim*8 exactly
    const int ch = lane * 4;
    int s = rptr[node], e = rptr[node + 1];
    float d = dinv[node];
    float dd = d * d;
    float4 h = bf4_to_f4(*(const uint2*)(Hb + (size_t)node * C + ch));
    float4 acc = make_float4(dd * h.x, dd * h.y, dd * h.z, dd * h.w);
    int j = s;
    for (; j + 2 <= e; j += 2) {
        int2 e0 = csr[j], e1 = csr[j + 1];
        float w0 = __int_as_float(e0.y), w1 = __int_as_float(e1.y);
        float4 v0 = bf4_to_f4(*(const uint2*)(Hb + (size_t)e0.x * C + ch));
        float4 v1 = bf4_to_f4(*(const uint2*)(Hb + (size_t)e1.x * C + ch));
        acc.x = fmaf(v0.x, w0, acc.x); acc.y = fmaf(v0.y, w0, acc.y);
        acc.z = fmaf(v0.z, w0, acc.z); acc.w = fmaf(v0.w, w0, acc.w);
        acc.x = fmaf(v1.x, w1, acc.x); acc.y = fmaf(v1.y, w1, acc.y);
        acc.z = fmaf(v1.z, w1, acc.z); acc.w = fmaf(v1.w, w1, acc.w);
    }
    if (j < e) {
        int2 e0 = csr[j];
        float w0 = __int_as_float(e0.y);
        float4 v0 = bf4_to_f4(*(const uint2*)(Hb + (size_t)e0.x * C + ch));
        acc.x = fmaf(v0.x, w0, acc.x); acc.y = fmaf(v0.y, w0, acc.y);
        acc.z = fmaf(v0.z, w0, acc.z); acc.w = fmaf(v0.w, w0, acc.w);
    }
    float4 b = *(const float4*)(bg + ch);
    acc.x += b.x; acc.y += b.y; acc.z += b.z; acc.w += b.w;
    *(float4*)(OUT + (size_t)node * C + ch) = acc;

    // ---- fused BN partials: reduce over the block's 8 nodes, no atomics ----
    __shared__ __align__(16) float4 sred[2][8][32];   // 8 KiB
    float4 sq = make_float4(acc.x * acc.x, acc.y * acc.y, acc.z * acc.z, acc.w * acc.w);
    sred[0][nl][lane] = acc;
    sred[1][nl][lane] = sq;
    __syncthreads();
    if (nl == 0) {
        float4 s0 = sred[0][0][lane], q0 = sred[1][0][lane];
#pragma unroll
        for (int k = 1; k < 8; k++) {
            float4 a = sred[0][k][lane];
            float4 q = sred[1][k][lane];
            s0.x += a.x; s0.y += a.y; s0.z += a.z; s0.w += a.w;
            q0.x += q.x; q0.y += q.y; q0.z += q.z; q0.w += q.w;
        }
        float* row = P + (size_t)blockIdx.x * 256;
        *(float4*)(row + ch) = s0;
        *(float4*)(row + 128 + ch) = q0;
    }
}

// ---------------- reduce spmm-block partials: P[6250][256] -> P2[128][256] ----------------
__global__ __launch_bounds__(256) void reduce1_kernel(const float* __restrict__ P,
                                                      float* __restrict__ P2) {
    const int c = threadIdx.x;
    const int r0 = blockIdx.x * RROWS;
    const int r1 = min(r0 + RROWS, SPB);
    float a0 = 0.f, a1 = 0.f, a2 = 0.f, a3 = 0.f;
    int r = r0;
    for (; r + 4 <= r1; r += 4) {
        a0 += P[(size_t)(r + 0) * 256 + c];
        a1 += P[(size_t)(r + 1) * 256 + c];
        a2 += P[(size_t)(r + 2) * 256 + c];
        a3 += P[(size_t)(r + 3) * 256 + c];
    }
    for (; r < r1; r++) a0 += P[(size_t)r * 256 + c];
    P2[(size_t)blockIdx.x * 256 + c] = (a0 + a1) + (a2 + a3);
}

// ---------------- BN params from P2 ----------------
__global__ void bnparam_kernel(const float* __restrict__ P2,
                               const float* __restrict__ gm, const float* __restrict__ bt,
                               float* __restrict__ sc, float* __restrict__ sh) {
    int c = threadIdx.x;   // 0..127
    float s0 = 0.f, s1 = 0.f, q0 = 0.f, q1 = 0.f;
    for (int k = 0; k < RB; k += 2) {
        s0 += P2[(size_t)k * 256 + c];
        q0 += P2[(size_t)k * 256 + 128 + c];
        s1 += P2[(size_t)(k + 1) * 256 + c];
        q1 += P2[(size_t)(k + 1) * 256 + 128 + c];
    }
    float ssum = s0 + s1, ssq = q0 + q1;
    float mean = ssum / (float)NN;
    float var = ssq / (float)NN - mean * mean;
    var = fmaxf(var, 0.f);
    float r = rsqrtf(var + BN_EPS);
    float s = gm[c] * r;
    sc[c] = s;
    sh[c] = bt[c] - mean * s;
}

// ---------------- final (MFMA): y = lrelu(BN(h)) @ W_lin + b_lin, in-place ----------------
// Each wave reads only its own 16 rows and writes only those rows -> in-place safe.
__global__ __launch_bounds__(256) void final_kernel(float* __restrict__ OUT,
                                                    const unsigned int* __restrict__ Wt,
                                                    const float* __restrict__ bl,
                                                    const float* __restrict__ sc,
                                                    const float* __restrict__ sh) {
    __shared__ unsigned int wsh[8192];   // 32 KB, swizzled [col][ku]
    const int t = threadIdx.x;
#pragma unroll
    for (int i = 0; i < 8; i++)
        ((uint4*)wsh)[t + i * 256] = ((const uint4*)Wt)[t + i * 256];

    const int lane = t & 63;
    const int wid = t >> 6;
    const int lrow = lane & 15;
    const int kb = lane >> 4;
    const int row = blockIdx.x * 64 + wid * 16 + lrow;
    const float* hrow = OUT + (size_t)min(row, NN - 1) * C;

    f32x4 acc[8];
#pragma unroll
    for (int n = 0; n < 8; n++) acc[n] = (f32x4){0.f, 0.f, 0.f, 0.f};
    __syncthreads();

#pragma unroll
    for (int ks = 0; ks < 4; ks++) {
        const int k0 = ks * 32 + kb * 8;
        float4 v0 = *(const float4*)(hrow + k0);
        float4 v1 = *(const float4*)(hrow + k0 + 4);
        float4 s0 = *(const float4*)(sc + k0);
        float4 s1 = *(const float4*)(sc + k0 + 4);
        float4 h0 = *(const float4*)(sh + k0);
        float4 h1 = *(const float4*)(sh + k0 + 4);
        float a[8];
        a[0] = fmaf(v0.x, s0.x, h0.x); a[1] = fmaf(v0.y, s0.y, h0.y);
        a[2] = fmaf(v0.z, s0.z, h0.z); a[3] = fmaf(v0.w, s0.w, h0.w);
        a[4] = fmaf(v1.x, s1.x, h1.x); a[5] = fmaf(v1.y, s1.y, h1.y);
        a[6] = fmaf(v1.z, s1.z, h1.z); a[7] = fmaf(v1.w, s1.w, h1.w);
#pragma unroll
        for (int i = 0; i < 8; i++) a[i] = a[i] >= 0.f ? a[i] : NEG * a[i];
        union { unsigned int u[4]; bf16x8 v; } af;
        af.u[0] = pack2(a[0], a[1]); af.u[1] = pack2(a[2], a[3]);
        af.u[2] = pack2(a[4], a[5]); af.u[3] = pack2(a[6], a[7]);
        const unsigned int gp = (unsigned int)((ks * 4 + kb) ^ lrow);
#pragma unroll
        for (int n = 0; n < 8; n++) {
            int col = n * 16 + lrow;
            union { uint4 q; bf16x8 v; } bfm;
            bfm.q = *(const uint4*)&wsh[col * 64 + gp * 4];
            acc[n] = __builtin_amdgcn_mfma_f32_16x16x32_bf16(af.v, bfm.v, acc[n], 0, 0, 0);
        }
    }
    const int orow = blockIdx.x * 64 + wid * 16 + kb * 4;
#pragma unroll
    for (int n = 0; n < 8; n++) {
        int col = n * 16 + lrow;
        float blv = bl[col];
#pragma unroll
        for (int i = 0; i < 4; i++) {
            int r = orow + i;
            if (r < NN) OUT[(size_t)r * C + col] = acc[n][i] + blv;
        }
    }
}

extern "C" void kernel_launch(void* const* d_in, const int* in_sizes, int n_in,
                              void* d_out, int out_size, void* d_ws, size_t ws_size,
                              hipStream_t stream) {
    const float* x  = (const float*)d_in[0];
    const int*   ei = (const int*)d_in[1];
    const float* ew = (const float*)d_in[2];
    const float* td = (const float*)d_in[3];
    const float* mf = (const float*)d_in[4];
    const float* Wg = (const float*)d_in[5];
    const float* bg = (const float*)d_in[6];
    const float* gm = (const float*)d_in[7];
    const float* bt = (const float*)d_in[8];
    const float* Wl = (const float*)d_in[9];
    const float* bl = (const float*)d_in[10];
    float* out = (float*)d_out;

    // workspace layout (all chunk sizes are multiples of 16 B)
    unsigned short* h1b = (unsigned short*)d_ws;         // NN*C bf16 (12.8 MB)
    unsigned long long* hist = (unsigned long long*)(h1b + (size_t)NN * C);  // NN u64 [zeroed]
    float* dinv   = (float*)(hist + NN);                 // NN
    float* cvec   = dinv + NN;                           // C
    float* sc     = cvec + C;                            // C
    float* sh     = sc + C;                              // C
    int*   rptr   = (int*)(sh + C);                      // NN+8
    int*   bsum   = rptr + NN + 8;                       // 196
    int*   boff   = bsum + NBLK;                         // 196 (+pad to keep 16B)
    int*   rank   = boff + NBLK + 8;                     // NE
    int2*  csr    = (int2*)(rank + NE);                  // NE int2
    float* P      = (float*)(csr + NE);                  // SPB*256 (6.4 MB)
    float* P2     = P + (size_t)SPB * 256;               // RB*256
    unsigned int* Wgt = (unsigned int*)(P2 + RB * 256);  // 8192 u32 (32 KB)
    unsigned int* Wlt = Wgt + 8192;                      // 8192 u32 (32 KB)

    zero_kernel<<<128, 256, 0, stream>>>((float*)hist, 2L * NN);
    wprep_kernel<<<1, 256, 0, stream>>>(Wg, Wl, Wgt, Wlt);
    cvec_kernel<<<1, 128, 0, stream>>>(td, mf, Wg, cvec);
    gemm1_kernel<<<GB, 256, 0, stream>>>(x, Wgt, cvec, h1b);
    hist_kernel<<<(NE + 255) / 256, 256, 0, stream>>>(ei, ew, hist, rank);
    scanp1_kernel<<<NBLK, 256, 0, stream>>>(hist, rptr, bsum);
    scanp2_kernel<<<1, 256, 0, stream>>>(bsum, boff);
    scanp3_kernel<<<NBLK, 256, 0, stream>>>(rptr, boff, hist, dinv);
    fill_kernel<<<(NE + 255) / 256, 256, 0, stream>>>(ei, ew, dinv, rptr, rank, csr);
    spmm_kernel<<<SPB, 256, 0, stream>>>(rptr, csr, h1b, dinv, bg, out, P);
    reduce1_kernel<<<RB, 256, 0, stream>>>(P, P2);
    bnparam_kernel<<<1, 128, 0, stream>>>(P2, gm, bt, sc, sh);
    final_kernel<<<GB, 256, 0, stream>>>(out, Wlt, bl, sc, sh);
}

// Round 8
// 140.121 us; speedup vs baseline: 7.2685x; 1.0552x over previous
//
#include <hip/hip_runtime.h>
#include <hip/hip_bf16.h>

#define NN 50000
#define NE 500000
#define C 128
#define NBLK ((NN + 255) / 256)       // 196 scan blocks
#define HISTB ((NE + 255) / 256)      // 1954 hist blocks
#define SPB (NN / 8)                  // 6250 spmm blocks (exact: 50000 = 6250*8)
#define RB 128                        // reduce1 blocks
#define RROWS ((SPB + RB - 1) / RB)   // 49 rows per reduce1 block
#define GB ((NN + 63) / 64)           // 782 gemm blocks
#define BN_EPS 1e-5f
#define NEG 0.01f
#define WSCALE 16777216.0f            // 2^24 fixed-point for packed degree
#define WMASK  0xFFFFFFFFFFFULL      // low 44 bits

typedef __attribute__((ext_vector_type(8))) short bf16x8;
typedef __attribute__((ext_vector_type(4))) float f32x4;

// bf16 helpers
__device__ inline unsigned short f2bf(float f) {            // round-to-nearest-even
    unsigned int u = __float_as_uint(f);
    unsigned int r = (u + 0x7fffu + ((u >> 16) & 1u)) >> 16;
    return (unsigned short)r;
}
__device__ inline unsigned int pack2(float a, float b) {
    return (unsigned int)f2bf(a) | ((unsigned int)f2bf(b) << 16);
}
__device__ inline float4 bf4_to_f4(uint2 u) {               // 4 packed bf16 -> 4 f32
    float4 r;
    r.x = __uint_as_float(u.x << 16);
    r.y = __uint_as_float(u.x & 0xffff0000u);
    r.z = __uint_as_float(u.y << 16);
    r.w = __uint_as_float(u.y & 0xffff0000u);
    return r;
}

// ---------------- setup: zero hist+counter | wprep | cvec (one dispatch) ----------------
// blocks 0..127: zero; block 128: wprep; block 129: cvec
__global__ __launch_bounds__(256) void setup_kernel(const float* __restrict__ Wg,
                                                    const float* __restrict__ Wl,
                                                    unsigned int* __restrict__ Wgt,
                                                    unsigned int* __restrict__ Wlt,
                                                    const float* __restrict__ td,
                                                    const float* __restrict__ mf,
                                                    float* __restrict__ cvec,
                                                    float* __restrict__ zreg) {
    const int b = blockIdx.x;
    const int t = threadIdx.x;
    if (b < 128) {
        long i = (long)b * 256 + t;
        const long n = 2L * NN + 4;        // hist (NN u64) + counter pad
        const long s = 128L * 256;
        for (; i < n; i += s) zreg[i] = 0.f;
    } else if (b == 128) {
        // W[k][c] f32 -> Wt[c][k] bf16 pairs, 16B-granule XOR swizzle
        const int col = t >> 1;
        const int half = t & 1;
        for (int j = 0; j < 32; j++) {
            int ku = half * 32 + j;
            int k0 = 2 * ku;
            unsigned int g = (unsigned int)((ku >> 2) ^ (col & 15));
            unsigned int slot = (unsigned int)col * 64u + (g << 2) + (unsigned int)(ku & 3);
            Wgt[slot] = pack2(Wg[(size_t)k0 * C + col], Wg[(size_t)(k0 + 1) * C + col]);
            Wlt[slot] = pack2(Wl[(size_t)k0 * C + col], Wl[(size_t)(k0 + 1) * C + col]);
        }
    } else {
        if (t < 128) {
            float tv = td[0];
            float acc = 0.f;
#pragma unroll
            for (int j = 0; j < 16; j++) {
                float s = sinf(tv * mf[j] * 3.14159265358979323846f);
                acc = fmaf(s, Wg[(128 + j) * C + t], acc);
            }
            cvec[t] = acc;
        }
    }
}

// ---------------- mega1: hist blocks (0..HISTB) then GEMM1 blocks ----------------
__global__ __launch_bounds__(256) void mega1_kernel(const float* __restrict__ X,
                                                    const unsigned int* __restrict__ Wt,
                                                    const float* __restrict__ cvec,
                                                    unsigned short* __restrict__ Hb,
                                                    const int* __restrict__ ei,
                                                    const float* __restrict__ ew,
                                                    unsigned long long* __restrict__ hist,
                                                    int* __restrict__ rank) {
    __shared__ unsigned int wsh[8192];   // 32 KB (allocated for all blocks; hist ignores)
    const int bid = blockIdx.x;
    const int t = threadIdx.x;
    if (bid < HISTB) {
        int e = bid * 256 + t;
        if (e < NE) {
            int c = ei[NE + e];
            unsigned long long pack = (1ULL << 44) | (unsigned long long)(ew[e] * WSCALE);
            unsigned long long old = atomicAdd(&hist[c], pack);
            rank[e] = (int)(old >> 44);
        }
        return;
    }
    const int gb = bid - HISTB;
#pragma unroll
    for (int i = 0; i < 8; i++)
        ((uint4*)wsh)[t + i * 256] = ((const uint4*)Wt)[t + i * 256];

    const int lane = t & 63;
    const int wid = t >> 6;
    const int lrow = lane & 15;
    const int kb = lane >> 4;            // 0..3
    const int row = gb * 64 + wid * 16 + lrow;
    const float* xrow = X + (size_t)min(row, NN - 1) * C;

    f32x4 acc[8];
#pragma unroll
    for (int n = 0; n < 8; n++) acc[n] = (f32x4){0.f, 0.f, 0.f, 0.f};
    __syncthreads();

#pragma unroll
    for (int ks = 0; ks < 4; ks++) {
        float4 a0 = *(const float4*)(xrow + ks * 32 + kb * 8);
        float4 a1 = *(const float4*)(xrow + ks * 32 + kb * 8 + 4);
        union { unsigned int u[4]; bf16x8 v; } af;
        af.u[0] = pack2(a0.x, a0.y); af.u[1] = pack2(a0.z, a0.w);
        af.u[2] = pack2(a1.x, a1.y); af.u[3] = pack2(a1.z, a1.w);
        const unsigned int gp = (unsigned int)((ks * 4 + kb) ^ lrow);
#pragma unroll
        for (int n = 0; n < 8; n++) {
            int col = n * 16 + lrow;
            union { uint4 q; bf16x8 v; } bfm;
            bfm.q = *(const uint4*)&wsh[col * 64 + gp * 4];
            acc[n] = __builtin_amdgcn_mfma_f32_16x16x32_bf16(af.v, bfm.v, acc[n], 0, 0, 0);
        }
    }
    const int orow = gb * 64 + wid * 16 + kb * 4;   // C/D: col=lane&15, row=(lane>>4)*4+i
#pragma unroll
    for (int n = 0; n < 8; n++) {
        int col = n * 16 + lrow;
        float cv = cvec[col];
#pragma unroll
        for (int i = 0; i < 4; i++) {
            int r = orow + i;
            if (r < NN) Hb[(size_t)r * C + col] = f2bf(acc[n][i] + cv);
        }
    }
}

// ---------------- scan pass 1: per-block exclusive scan of decoded counts ----------------
__global__ __launch_bounds__(256) void scanp1_kernel(const unsigned long long* __restrict__ hist,
                                                     int* __restrict__ rptr,
                                                     int* __restrict__ bsum) {
    __shared__ int s[256];
    const int t = threadIdx.x;
    const int i = blockIdx.x * 256 + t;
    int v = (i < NN) ? (int)(hist[i] >> 44) : 0;
    s[t] = v;
    __syncthreads();
    for (int off = 1; off < 256; off <<= 1) {
        int add = (t >= off) ? s[t - off] : 0;
        __syncthreads();
        s[t] += add;
        __syncthreads();
    }
    if (i < NN) rptr[i] = s[t] - v;           // exclusive within block
    if (t == 255) bsum[blockIdx.x] = s[255];  // block total
}

// ---------------- scan pass 2 (fused): block offset = sum(bsum[0..b-1]); + dinv ----------------
__global__ __launch_bounds__(256) void scanp3_kernel(int* __restrict__ rptr,
                                                     const int* __restrict__ bsum,
                                                     const unsigned long long* __restrict__ hist,
                                                     float* __restrict__ dinv) {
    __shared__ int sb[256];
    const int t = threadIdx.x;
    const int b = blockIdx.x;
    sb[t] = (t < NBLK && t < b) ? bsum[t] : 0;
    __syncthreads();
    for (int off = 128; off > 0; off >>= 1) {
        if (t < off) sb[t] += sb[t + off];
        __syncthreads();
    }
    const int boff = sb[0];
    const int i = b * 256 + t;
    if (i < NN) {
        rptr[i] += boff;
        float degw = (float)(hist[i] & WMASK) * (1.0f / WSCALE);
        dinv[i] = rsqrtf(degw + 1.0f);   // +1 self-loop; always > 0
    }
    if (b == 0 && t == 0) rptr[NN] = NE; // total is a constant
}

// ---------------- fill CSR: no atomic — slot = rptr[c] + rank[e] ----------------
__global__ void fill_kernel(const int* __restrict__ ei, const float* __restrict__ ew,
                            const float* __restrict__ dinv, const int* __restrict__ rptr,
                            const int* __restrict__ rank, int2* __restrict__ csr) {
    int e = blockIdx.x * blockDim.x + threadIdx.x;
    if (e >= NE) return;
    int r = ei[e], c = ei[NE + e];
    int slot = rptr[c] + rank[e];
    float w = dinv[r] * ew[e] * dinv[c];
    csr[slot] = make_int2(r, __float_as_int(w));
}

// ---------------- SpMM (bf16 gather, f32 accum, unroll-4) + fused BN partials ----------------
__global__ __launch_bounds__(256) void spmm_kernel(const int* __restrict__ rptr,
                                                   const int2* __restrict__ csr,
                                                   const unsigned short* __restrict__ Hb,
                                                   const float* __restrict__ dinv,
                                                   const float* __restrict__ bg,
                                                   float* __restrict__ OUT,
                                                   float* __restrict__ P) {
    const int nl = threadIdx.x >> 5;                 // node lane 0..7
    const int lane = threadIdx.x & 31;               // channel-group lane
    const int node = blockIdx.x * 8 + nl;            // NN == gridDim*8 exactly
    const int ch = lane * 4;
    int s = rptr[node], e = rptr[node + 1];
    float d = dinv[node];
    float dd = d * d;
    float4 h = bf4_to_f4(*(const uint2*)(Hb + (size_t)node * C + ch));
    float4 acc = make_float4(dd * h.x, dd * h.y, dd * h.z, dd * h.w);
    float4 accB = make_float4(0.f, 0.f, 0.f, 0.f);
    int j = s;
    for (; j + 4 <= e; j += 4) {
        int2 e0 = csr[j], e1 = csr[j + 1], e2 = csr[j + 2], e3 = csr[j + 3];
        float w0 = __int_as_float(e0.y), w1 = __int_as_float(e1.y);
        float w2 = __int_as_float(e2.y), w3 = __int_as_float(e3.y);
        uint2 u0 = *(const uint2*)(Hb + (size_t)e0.x * C + ch);
        uint2 u1 = *(const uint2*)(Hb + (size_t)e1.x * C + ch);
        uint2 u2 = *(const uint2*)(Hb + (size_t)e2.x * C + ch);
        uint2 u3 = *(const uint2*)(Hb + (size_t)e3.x * C + ch);
        float4 v0 = bf4_to_f4(u0), v1 = bf4_to_f4(u1), v2 = bf4_to_f4(u2), v3 = bf4_to_f4(u3);
        acc.x = fmaf(v0.x, w0, acc.x);  acc.y = fmaf(v0.y, w0, acc.y);
        acc.z = fmaf(v0.z, w0, acc.z);  acc.w = fmaf(v0.w, w0, acc.w);
        accB.x = fmaf(v1.x, w1, accB.x); accB.y = fmaf(v1.y, w1, accB.y);
        accB.z = fmaf(v1.z, w1, accB.z); accB.w = fmaf(v1.w, w1, accB.w);
        acc.x = fmaf(v2.x, w2, acc.x);  acc.y = fmaf(v2.y, w2, acc.y);
        acc.z = fmaf(v2.z, w2, acc.z);  acc.w = fmaf(v2.w, w2, acc.w);
        accB.x = fmaf(v3.x, w3, accB.x); accB.y = fmaf(v3.y, w3, accB.y);
        accB.z = fmaf(v3.z, w3, accB.z); accB.w = fmaf(v3.w, w3, accB.w);
    }
    for (; j < e; j++) {
        int2 e0 = csr[j];
        float w0 = __int_as_float(e0.y);
        float4 v0 = bf4_to_f4(*(const uint2*)(Hb + (size_t)e0.x * C + ch));
        acc.x = fmaf(v0.x, w0, acc.x); acc.y = fmaf(v0.y, w0, acc.y);
        acc.z = fmaf(v0.z, w0, acc.z); acc.w = fmaf(v0.w, w0, acc.w);
    }
    acc.x += accB.x; acc.y += accB.y; acc.z += accB.z; acc.w += accB.w;
    float4 b = *(const float4*)(bg + ch);
    acc.x += b.x; acc.y += b.y; acc.z += b.z; acc.w += b.w;
    *(float4*)(OUT + (size_t)node * C + ch) = acc;

    // ---- fused BN partials: reduce over the block's 8 nodes, no atomics ----
    __shared__ __align__(16) float4 sred[2][8][32];   // 8 KiB
    float4 sq = make_float4(acc.x * acc.x, acc.y * acc.y, acc.z * acc.z, acc.w * acc.w);
    sred[0][nl][lane] = acc;
    sred[1][nl][lane] = sq;
    __syncthreads();
    if (nl == 0) {
        float4 s0 = sred[0][0][lane], q0 = sred[1][0][lane];
#pragma unroll
        for (int k = 1; k < 8; k++) {
            float4 a = sred[0][k][lane];
            float4 q = sred[1][k][lane];
            s0.x += a.x; s0.y += a.y; s0.z += a.z; s0.w += a.w;
            q0.x += q.x; q0.y += q.y; q0.z += q.z; q0.w += q.w;
        }
        float* row = P + (size_t)blockIdx.x * 256;
        *(float4*)(row + ch) = s0;
        *(float4*)(row + 128 + ch) = q0;
    }
}

// ---------------- reduce1 + fused bnparam (last-block pattern) ----------------
__global__ __launch_bounds__(256) void reduce1_kernel(const float* __restrict__ P,
                                                      float* __restrict__ P2,
                                                      unsigned int* __restrict__ cnt,
                                                      const float* __restrict__ gm,
                                                      const float* __restrict__ bt,
                                                      float* __restrict__ sc,
                                                      float* __restrict__ sh) {
    const int c = threadIdx.x;
    const int r0 = blockIdx.x * RROWS;
    const int r1 = min(r0 + RROWS, SPB);
    float a0 = 0.f, a1 = 0.f, a2 = 0.f, a3 = 0.f;
    int r = r0;
    for (; r + 4 <= r1; r += 4) {
        a0 += P[(size_t)(r + 0) * 256 + c];
        a1 += P[(size_t)(r + 1) * 256 + c];
        a2 += P[(size_t)(r + 2) * 256 + c];
        a3 += P[(size_t)(r + 3) * 256 + c];
    }
    for (; r < r1; r++) a0 += P[(size_t)r * 256 + c];
    P2[(size_t)blockIdx.x * 256 + c] = (a0 + a1) + (a2 + a3);

    __threadfence();
    __shared__ unsigned int done;
    if (c == 0) done = atomicAdd(cnt, 1u);
    __syncthreads();
    if (done == RB - 1) {
        __threadfence();   // acquire: see all P2 rows
        if (c < 128) {
            float s0 = 0.f, s1 = 0.f, q0 = 0.f, q1 = 0.f;
            for (int k = 0; k < RB; k += 2) {
                s0 += P2[(size_t)k * 256 + c];
                q0 += P2[(size_t)k * 256 + 128 + c];
                s1 += P2[(size_t)(k + 1) * 256 + c];
                q1 += P2[(size_t)(k + 1) * 256 + 128 + c];
            }
            float ssum = s0 + s1, ssq = q0 + q1;
            float mean = ssum / (float)NN;
            float var = ssq / (float)NN - mean * mean;
            var = fmaxf(var, 0.f);
            float rs = rsqrtf(var + BN_EPS);
            float s = gm[c] * rs;
            sc[c] = s;
            sh[c] = bt[c] - mean * s;
        }
    }
}

// ---------------- final (MFMA): y = lrelu(BN(h)) @ W_lin + b_lin, in-place ----------------
__global__ __launch_bounds__(256) void final_kernel(float* __restrict__ OUT,
                                                    const unsigned int* __restrict__ Wt,
                                                    const float* __restrict__ bl,
                                                    const float* __restrict__ sc,
                                                    const float* __restrict__ sh) {
    __shared__ unsigned int wsh[8192];   // 32 KB, swizzled [col][ku]
    const int t = threadIdx.x;
#pragma unroll
    for (int i = 0; i < 8; i++)
        ((uint4*)wsh)[t + i * 256] = ((const uint4*)Wt)[t + i * 256];

    const int lane = t & 63;
    const int wid = t >> 6;
    const int lrow = lane & 15;
    const int kb = lane >> 4;
    const int row = blockIdx.x * 64 + wid * 16 + lrow;
    const float* hrow = OUT + (size_t)min(row, NN - 1) * C;

    f32x4 acc[8];
#pragma unroll
    for (int n = 0; n < 8; n++) acc[n] = (f32x4){0.f, 0.f, 0.f, 0.f};
    __syncthreads();

#pragma unroll
    for (int ks = 0; ks < 4; ks++) {
        const int k0 = ks * 32 + kb * 8;
        float4 v0 = *(const float4*)(hrow + k0);
        float4 v1 = *(const float4*)(hrow + k0 + 4);
        float4 s0 = *(const float4*)(sc + k0);
        float4 s1 = *(const float4*)(sc + k0 + 4);
        float4 h0 = *(const float4*)(sh + k0);
        float4 h1 = *(const float4*)(sh + k0 + 4);
        float a[8];
        a[0] = fmaf(v0.x, s0.x, h0.x); a[1] = fmaf(v0.y, s0.y, h0.y);
        a[2] = fmaf(v0.z, s0.z, h0.z); a[3] = fmaf(v0.w, s0.w, h0.w);
        a[4] = fmaf(v1.x, s1.x, h1.x); a[5] = fmaf(v1.y, s1.y, h1.y);
        a[6] = fmaf(v1.z, s1.z, h1.z); a[7] = fmaf(v1.w, s1.w, h1.w);
#pragma unroll
        for (int i = 0; i < 8; i++) a[i] = a[i] >= 0.f ? a[i] : NEG * a[i];
        union { unsigned int u[4]; bf16x8 v; } af;
        af.u[0] = pack2(a[0], a[1]); af.u[1] = pack2(a[2], a[3]);
        af.u[2] = pack2(a[4], a[5]); af.u[3] = pack2(a[6], a[7]);
        const unsigned int gp = (unsigned int)((ks * 4 + kb) ^ lrow);
#pragma unroll
        for (int n = 0; n < 8; n++) {
            int col = n * 16 + lrow;
            union { uint4 q; bf16x8 v; } bfm;
            bfm.q = *(const uint4*)&wsh[col * 64 + gp * 4];
            acc[n] = __builtin_amdgcn_mfma_f32_16x16x32_bf16(af.v, bfm.v, acc[n], 0, 0, 0);
        }
    }
    const int orow = blockIdx.x * 64 + wid * 16 + kb * 4;
#pragma unroll
    for (int n = 0; n < 8; n++) {
        int col = n * 16 + lrow;
        float blv = bl[col];
#pragma unroll
        for (int i = 0; i < 4; i++) {
            int r = orow + i;
            if (r < NN) OUT[(size_t)r * C + col] = acc[n][i] + blv;
        }
    }
}

extern "C" void kernel_launch(void* const* d_in, const int* in_sizes, int n_in,
                              void* d_out, int out_size, void* d_ws, size_t ws_size,
                              hipStream_t stream) {
    const float* x  = (const float*)d_in[0];
    const int*   ei = (const int*)d_in[1];
    const float* ew = (const float*)d_in[2];
    const float* td = (const float*)d_in[3];
    const float* mf = (const float*)d_in[4];
    const float* Wg = (const float*)d_in[5];
    const float* bg = (const float*)d_in[6];
    const float* gm = (const float*)d_in[7];
    const float* bt = (const float*)d_in[8];
    const float* Wl = (const float*)d_in[9];
    const float* bl = (const float*)d_in[10];
    float* out = (float*)d_out;

    // workspace layout (all chunk sizes are multiples of 16 B)
    unsigned short* h1b = (unsigned short*)d_ws;         // NN*C bf16 (12.8 MB)
    unsigned long long* hist = (unsigned long long*)(h1b + (size_t)NN * C);  // NN u64 [zeroed]
    unsigned int* cnt = (unsigned int*)(hist + NN);      // 4 u32 [zeroed]
    float* dinv   = (float*)(cnt + 4);                   // NN
    float* cvec   = dinv + NN;                           // C
    float* sc     = cvec + C;                            // C
    float* sh     = sc + C;                              // C
    int*   rptr   = (int*)(sh + C);                      // NN+8
    int*   bsum   = rptr + NN + 8;                       // 196 (+pad)
    int*   rank   = bsum + NBLK + 12;                    // NE
    int2*  csr    = (int2*)(rank + NE);                  // NE int2
    float* P      = (float*)(csr + NE);                  // SPB*256 (6.4 MB)
    float* P2     = P + (size_t)SPB * 256;               // RB*256
    unsigned int* Wgt = (unsigned int*)(P2 + RB * 256);  // 8192 u32 (32 KB)
    unsigned int* Wlt = Wgt + 8192;                      // 8192 u32 (32 KB)

    setup_kernel<<<130, 256, 0, stream>>>(Wg, Wl, Wgt, Wlt, td, mf, cvec, (float*)hist);
    mega1_kernel<<<HISTB + GB, 256, 0, stream>>>(x, Wgt, cvec, h1b, ei, ew, hist, rank);
    scanp1_kernel<<<NBLK, 256, 0, stream>>>(hist, rptr, bsum);
    scanp3_kernel<<<NBLK, 256, 0, stream>>>(rptr, bsum, hist, dinv);
    fill_kernel<<<HISTB, 256, 0, stream>>>(ei, ew, dinv, rptr, rank, csr);
    spmm_kernel<<<SPB, 256, 0, stream>>>(rptr, csr, h1b, dinv, bg, out, P);
    reduce1_kernel<<<RB, 256, 0, stream>>>(P, P2, cnt, gm, bt, sc, sh);
    final_kernel<<<GB, 256, 0, stream>>>(out, Wlt, bl, sc, sh);
}